// Round 7
// baseline (655.536 us; speedup 1.0000x reference)
//
#include <hip/hip_runtime.h>
#include <hip/hip_fp8.h>

// ---------------------------------------------------------------------------
// SAGEMultiSwitchModel: 2 heads x 2 SAGE layers on N=100k nodes, E=1.6M edges.
// head0 dirs "OI", head1 "UU". Layer: act([h|seg_mean(h)] @ [Ws|Wn]^T + b).
// R1: spill-free gemm. R2: bf16 gather tables. R4: bucketed-sort CSR build.
// R5: MFMA gemms (A-frags in regs, B = untransposed bf16 weights).
// R6: fp8-e4m3 x-gather table for L0 agg (64B rows, halves L0 gather bytes);
//     fused L0 gemm pair; NT loads for adj streams / NT stores for outputs.
// Measured ceiling: random-row gathers pin at ~2.55 TB/s HBM-side miss BW;
// both L1 agg passes hit it (FETCH 352 MB @ 138us each).
// ---------------------------------------------------------------------------

typedef unsigned short u16;
typedef unsigned int u32;
typedef unsigned char u8;
typedef __bf16 bf16x8 __attribute__((ext_vector_type(8)));
typedef float f32x4 __attribute__((ext_vector_type(4)));

__device__ __forceinline__ u32 f2bf(float f) {  // RNE float->bf16 (low 16 bits)
    u32 u = __float_as_uint(f);
    return (u + 0x7fffu + ((u >> 16) & 1u)) >> 16;
}
__device__ __forceinline__ float bf_lo(u32 v) { return __uint_as_float(v << 16); }
__device__ __forceinline__ float bf_hi(u32 v) { return __uint_as_float(v & 0xffff0000u); }
__device__ __forceinline__ u8 f2q(float f) {  // float -> fp8 e4m3 (OCP)
    __hip_fp8_e4m3 t(f);
    return *(u8*)&t;
}
__device__ __forceinline__ float q2f(u8 b) {
    __hip_fp8_e4m3 t;
    *(u8*)&t = b;
    return (float)t;
}

// fused prep: zero cnt[1024]; x -> bf16 xb AND fp8 xq; weights -> bf16 flat
__global__ void k_prep(const float* __restrict__ x, u16* __restrict__ xb,
                       u8* __restrict__ xq, int n4, int* __restrict__ cntzero,
                       const float* __restrict__ Ws0, const float* __restrict__ Wn0,
                       const float* __restrict__ Ws1, const float* __restrict__ Wn1,
                       u16* __restrict__ Wsb0, u16* __restrict__ Wnb0,
                       u16* __restrict__ Wsb1, u16* __restrict__ Wnb1) {
    int i = blockIdx.x * blockDim.x + threadIdx.x;
    if (i < 1024) cntzero[i] = 0;
    if (i < n4) {
        float4 v = *(const float4*)&x[(size_t)i * 4];
        u32 p0 = f2bf(v.x) | (f2bf(v.y) << 16);
        u32 p1 = f2bf(v.z) | (f2bf(v.w) << 16);
        *(uint2*)&xb[(size_t)i * 4] = make_uint2(p0, p1);
        u32 q = (u32)f2q(v.x) | ((u32)f2q(v.y) << 8) |
                ((u32)f2q(v.z) << 16) | ((u32)f2q(v.w) << 24);
        *(u32*)&xq[(size_t)i * 4] = q;
        return;
    }
    int t = i - n4;
    if (t < 16384) Wsb0[t] = (u16)f2bf(Ws0[t]);
    else if (t < 32768) Wnb0[t - 16384] = (u16)f2bf(Wn0[t - 16384]);
    else if (t < 65536) Wsb1[t - 32768] = (u16)f2bf(Ws1[t - 32768]);
    else if (t < 98304) Wnb1[t - 65536] = (u16)f2bf(Wn1[t - 65536]);
}

// ---- bucketed CSR build: NPB=256 nodes/bucket, bucket = node>>8 ----

__global__ void __launch_bounds__(256) k_bincnt(
        const int* __restrict__ src, const int* __restrict__ dst,
        int* cntD, int* cntS, int E, int NB) {
    __shared__ int hD[512], hS[512];
    const int tid = threadIdx.x;
    for (int i = tid; i < NB; i += 256) { hD[i] = 0; hS[i] = 0; }
    __syncthreads();
    const int base = (blockIdx.x * 256 + tid) * 8;
#pragma unroll
    for (int i = 0; i < 8; i++) {
        if (base + i < E) {
            atomicAdd(&hD[dst[base + i] >> 8], 1);
            atomicAdd(&hS[src[base + i] >> 8], 1);
        }
    }
    __syncthreads();
    for (int i = tid; i < NB; i += 256) {
        if (hD[i]) atomicAdd(&cntD[i], hD[i]);
        if (hS[i]) atomicAdd(&cntS[i], hS[i]);
    }
}

__global__ void __launch_bounds__(512) k_binscan(
        const int* __restrict__ cntD, const int* __restrict__ cntS,
        int* bbaseD, int* bbaseS, int* curD, int* curS,
        int* off_in, int* off_out, int NB, int N, int E) {
    __shared__ int ts[512];
    const int tid = threadIdx.x;
    int v = (tid < NB) ? cntD[tid] : 0;
    ts[tid] = v;
    __syncthreads();
    for (int ofs = 1; ofs < 512; ofs <<= 1) {
        int t = (tid >= ofs) ? ts[tid - ofs] : 0;
        __syncthreads();
        ts[tid] += t;
        __syncthreads();
    }
    int ex = ts[tid] - v;
    if (tid < NB) { bbaseD[tid] = ex; curD[tid] = ex; }
    if (tid == NB - 1) bbaseD[NB] = ex + v;
    __syncthreads();
    v = (tid < NB) ? cntS[tid] : 0;
    ts[tid] = v;
    __syncthreads();
    for (int ofs = 1; ofs < 512; ofs <<= 1) {
        int t = (tid >= ofs) ? ts[tid - ofs] : 0;
        __syncthreads();
        ts[tid] += t;
        __syncthreads();
    }
    ex = ts[tid] - v;
    if (tid < NB) { bbaseS[tid] = ex; curS[tid] = ex; }
    if (tid == NB - 1) bbaseS[NB] = ex + v;
    if (tid == 0) { off_in[N] = E; off_out[N] = E; }
}

__global__ void __launch_bounds__(256) k_binscatter(
        const int* __restrict__ src, const int* __restrict__ dst,
        int* curD, int* curS, u32* __restrict__ pairsD, u32* __restrict__ pairsS,
        int E, int NB) {
    __shared__ int hD[512], hS[512], bD[512], bS[512];
    const int tid = threadIdx.x;
    for (int i = tid; i < NB; i += 256) { hD[i] = 0; hS[i] = 0; }
    __syncthreads();
    const int base = (blockIdx.x * 256 + tid) * 8;
    int sv[8], dv[8], rD[8], rS[8];
#pragma unroll
    for (int i = 0; i < 8; i++) {
        if (base + i < E) {
            sv[i] = src[base + i];
            dv[i] = dst[base + i];
            rD[i] = atomicAdd(&hD[dv[i] >> 8], 1);
            rS[i] = atomicAdd(&hS[sv[i] >> 8], 1);
        }
    }
    __syncthreads();
    for (int i = tid; i < NB; i += 256) {
        bD[i] = hD[i] ? atomicAdd(&curD[i], hD[i]) : 0;
        bS[i] = hS[i] ? atomicAdd(&curS[i], hS[i]) : 0;
    }
    __syncthreads();
#pragma unroll
    for (int i = 0; i < 8; i++) {
        if (base + i < E) {
            pairsD[bD[dv[i] >> 8] + rD[i]] = ((u32)(dv[i] & 255) << 24) | (u32)sv[i];
            pairsS[bS[sv[i] >> 8] + rS[i]] = ((u32)(sv[i] & 255) << 24) | (u32)dv[i];
        }
    }
}

__global__ void __launch_bounds__(256) k_bucket_csr(
        const u32* __restrict__ pairsD, const u32* __restrict__ pairsS,
        const int* __restrict__ bbaseD, const int* __restrict__ bbaseS,
        int* __restrict__ off_in, int* __restrict__ adj_in,
        int* __restrict__ off_out, int* __restrict__ adj_out, int N) {
    __shared__ int cnt[256], cur[256], ts[256];
    const int b = blockIdx.x >> 1;
    const int arr = blockIdx.x & 1;
    const u32* pairs = arr ? pairsS : pairsD;
    const int* bbase = arr ? bbaseS : bbaseD;
    int* off = arr ? off_out : off_in;
    int* adj = arr ? adj_out : adj_in;
    const int e0 = bbase[b], e1 = bbase[b + 1];
    const int tid = threadIdx.x;
    cnt[tid] = 0;
    __syncthreads();
    for (int e = e0 + tid; e < e1; e += 256) atomicAdd(&cnt[pairs[e] >> 24], 1);
    __syncthreads();
    int v = cnt[tid];
    ts[tid] = v;
    __syncthreads();
    for (int ofs = 1; ofs < 256; ofs <<= 1) {
        int t = (tid >= ofs) ? ts[tid - ofs] : 0;
        __syncthreads();
        ts[tid] += t;
        __syncthreads();
    }
    const int ex = ts[tid] - v;
    const int n = b * 256 + tid;
    if (n < N) off[n] = e0 + ex;
    cur[tid] = e0 + ex;
    __syncthreads();
    for (int e = e0 + tid; e < e1; e += 256) {
        u32 p = pairs[e];
        int w = atomicAdd(&cur[p >> 24], 1);
        adj[w] = (int)(p & 0xFFFFFFu);
    }
}

// layer-0 aggregation: F=64 fp8 gather (1 byte/lane, 64B/row), x8 unrolled.
__global__ void __launch_bounds__(256) k_agg_l0_q(
        const u8* __restrict__ xq,
        const int* __restrict__ off_in, const int* __restrict__ adj_in,
        const int* __restrict__ off_out, const int* __restrict__ adj_out,
        u16* __restrict__ agg0b, u16* __restrict__ aggUb, int n) {
    const int node = blockIdx.x * 4 + (threadIdx.x >> 6);
    const int lane = threadIdx.x & 63;
    if (node >= n) return;
    const int a0 = off_in[node], a1 = off_in[node + 1];
    const int b0 = off_out[node], b1 = off_out[node + 1];
    float sin_ = 0.f, sout_ = 0.f;
    int j = a0;
    for (; j + 7 < a1; j += 8) {
        int i0 = __builtin_nontemporal_load(&adj_in[j]);
        int i1 = __builtin_nontemporal_load(&adj_in[j + 1]);
        int i2 = __builtin_nontemporal_load(&adj_in[j + 2]);
        int i3 = __builtin_nontemporal_load(&adj_in[j + 3]);
        int i4 = __builtin_nontemporal_load(&adj_in[j + 4]);
        int i5 = __builtin_nontemporal_load(&adj_in[j + 5]);
        int i6 = __builtin_nontemporal_load(&adj_in[j + 6]);
        int i7 = __builtin_nontemporal_load(&adj_in[j + 7]);
        float v0 = q2f(xq[(size_t)i0 * 64 + lane]);
        float v1 = q2f(xq[(size_t)i1 * 64 + lane]);
        float v2 = q2f(xq[(size_t)i2 * 64 + lane]);
        float v3 = q2f(xq[(size_t)i3 * 64 + lane]);
        float v4 = q2f(xq[(size_t)i4 * 64 + lane]);
        float v5 = q2f(xq[(size_t)i5 * 64 + lane]);
        float v6 = q2f(xq[(size_t)i6 * 64 + lane]);
        float v7 = q2f(xq[(size_t)i7 * 64 + lane]);
        sin_ += ((v0 + v1) + (v2 + v3)) + ((v4 + v5) + (v6 + v7));
    }
    for (; j < a1; j++) sin_ += q2f(xq[(size_t)adj_in[j] * 64 + lane]);
    j = b0;
    for (; j + 7 < b1; j += 8) {
        int i0 = __builtin_nontemporal_load(&adj_out[j]);
        int i1 = __builtin_nontemporal_load(&adj_out[j + 1]);
        int i2 = __builtin_nontemporal_load(&adj_out[j + 2]);
        int i3 = __builtin_nontemporal_load(&adj_out[j + 3]);
        int i4 = __builtin_nontemporal_load(&adj_out[j + 4]);
        int i5 = __builtin_nontemporal_load(&adj_out[j + 5]);
        int i6 = __builtin_nontemporal_load(&adj_out[j + 6]);
        int i7 = __builtin_nontemporal_load(&adj_out[j + 7]);
        float v0 = q2f(xq[(size_t)i0 * 64 + lane]);
        float v1 = q2f(xq[(size_t)i1 * 64 + lane]);
        float v2 = q2f(xq[(size_t)i2 * 64 + lane]);
        float v3 = q2f(xq[(size_t)i3 * 64 + lane]);
        float v4 = q2f(xq[(size_t)i4 * 64 + lane]);
        float v5 = q2f(xq[(size_t)i5 * 64 + lane]);
        float v6 = q2f(xq[(size_t)i6 * 64 + lane]);
        float v7 = q2f(xq[(size_t)i7 * 64 + lane]);
        sout_ += ((v0 + v1) + (v2 + v3)) + ((v4 + v5) + (v6 + v7));
    }
    for (; j < b1; j++) sout_ += q2f(xq[(size_t)adj_out[j] * 64 + lane]);
    const int din = a1 - a0, dout = b1 - b0;
    const int du = din + dout;
    u16 r0 = (u16)f2bf(din ? sin_ / (float)din : 0.f);
    u16 rU = (u16)f2bf(du ? (sin_ + sout_) / (float)du : 0.f);
    __builtin_nontemporal_store(r0, &agg0b[(size_t)node * 64 + lane]);
    __builtin_nontemporal_store(rU, &aggUb[(size_t)node * 64 + lane]);
}

// layer-1 aggregation: F=128 bf16 gather (lane reads packed u32 pair), x8.
__global__ void __launch_bounds__(256) k_agg_l1_b(
        const u16* __restrict__ Hb,
        const int* __restrict__ offA, const int* __restrict__ adjA,
        const int* __restrict__ offB, const int* __restrict__ adjB,
        u16* __restrict__ outb, int n) {
    const int node = blockIdx.x * 4 + (threadIdx.x >> 6);
    const int lane = threadIdx.x & 63;
    if (node >= n) return;
    float s0 = 0.f, s1 = 0.f;
    const int a0 = offA[node], a1 = offA[node + 1];
    int j = a0;
    for (; j + 7 < a1; j += 8) {
        int i0 = __builtin_nontemporal_load(&adjA[j]);
        int i1 = __builtin_nontemporal_load(&adjA[j + 1]);
        int i2 = __builtin_nontemporal_load(&adjA[j + 2]);
        int i3 = __builtin_nontemporal_load(&adjA[j + 3]);
        int i4 = __builtin_nontemporal_load(&adjA[j + 4]);
        int i5 = __builtin_nontemporal_load(&adjA[j + 5]);
        int i6 = __builtin_nontemporal_load(&adjA[j + 6]);
        int i7 = __builtin_nontemporal_load(&adjA[j + 7]);
        u32 v0 = *(const u32*)&Hb[(size_t)i0 * 128 + lane * 2];
        u32 v1 = *(const u32*)&Hb[(size_t)i1 * 128 + lane * 2];
        u32 v2 = *(const u32*)&Hb[(size_t)i2 * 128 + lane * 2];
        u32 v3 = *(const u32*)&Hb[(size_t)i3 * 128 + lane * 2];
        u32 v4 = *(const u32*)&Hb[(size_t)i4 * 128 + lane * 2];
        u32 v5 = *(const u32*)&Hb[(size_t)i5 * 128 + lane * 2];
        u32 v6 = *(const u32*)&Hb[(size_t)i6 * 128 + lane * 2];
        u32 v7 = *(const u32*)&Hb[(size_t)i7 * 128 + lane * 2];
        s0 += ((bf_lo(v0) + bf_lo(v1)) + (bf_lo(v2) + bf_lo(v3))) +
              ((bf_lo(v4) + bf_lo(v5)) + (bf_lo(v6) + bf_lo(v7)));
        s1 += ((bf_hi(v0) + bf_hi(v1)) + (bf_hi(v2) + bf_hi(v3))) +
              ((bf_hi(v4) + bf_hi(v5)) + (bf_hi(v6) + bf_hi(v7)));
    }
    for (; j < a1; j++) {
        u32 v = *(const u32*)&Hb[(size_t)adjA[j] * 128 + lane * 2];
        s0 += bf_lo(v);
        s1 += bf_hi(v);
    }
    int deg = a1 - a0;
    if (offB) {
        const int b0 = offB[node], b1 = offB[node + 1];
        j = b0;
        for (; j + 7 < b1; j += 8) {
            int i0 = __builtin_nontemporal_load(&adjB[j]);
            int i1 = __builtin_nontemporal_load(&adjB[j + 1]);
            int i2 = __builtin_nontemporal_load(&adjB[j + 2]);
            int i3 = __builtin_nontemporal_load(&adjB[j + 3]);
            int i4 = __builtin_nontemporal_load(&adjB[j + 4]);
            int i5 = __builtin_nontemporal_load(&adjB[j + 5]);
            int i6 = __builtin_nontemporal_load(&adjB[j + 6]);
            int i7 = __builtin_nontemporal_load(&adjB[j + 7]);
            u32 v0 = *(const u32*)&Hb[(size_t)i0 * 128 + lane * 2];
            u32 v1 = *(const u32*)&Hb[(size_t)i1 * 128 + lane * 2];
            u32 v2 = *(const u32*)&Hb[(size_t)i2 * 128 + lane * 2];
            u32 v3 = *(const u32*)&Hb[(size_t)i3 * 128 + lane * 2];
            u32 v4 = *(const u32*)&Hb[(size_t)i4 * 128 + lane * 2];
            u32 v5 = *(const u32*)&Hb[(size_t)i5 * 128 + lane * 2];
            u32 v6 = *(const u32*)&Hb[(size_t)i6 * 128 + lane * 2];
            u32 v7 = *(const u32*)&Hb[(size_t)i7 * 128 + lane * 2];
            s0 += ((bf_lo(v0) + bf_lo(v1)) + (bf_lo(v2) + bf_lo(v3))) +
                  ((bf_lo(v4) + bf_lo(v5)) + (bf_lo(v6) + bf_lo(v7)));
            s1 += ((bf_hi(v0) + bf_hi(v1)) + (bf_hi(v2) + bf_hi(v3))) +
                  ((bf_hi(v4) + bf_hi(v5)) + (bf_hi(v6) + bf_hi(v7)));
        }
        for (; j < b1; j++) {
            u32 v = *(const u32*)&Hb[(size_t)adjB[j] * 128 + lane * 2];
            s0 += bf_lo(v);
            s1 += bf_hi(v);
        }
        deg += b1 - b0;
    }
    float inv = deg ? 1.f / (float)deg : 0.f;
    u32 p = f2bf(s0 * inv) | (f2bf(s1 * inv) << 16);
    __builtin_nontemporal_store(p, (u32*)&outb[(size_t)node * 128 + lane * 2]);
}

// MFMA dual-GEMM tile body: 16 rows x 128 cols per wave, A-frags in regs,
// B-frags read directly from untransposed bf16 weights [128][K].
// Layouts (gfx950 16x16x32 bf16): A row=lane&15, k=8*(lane>>4)+j; B col=lane&15;
// C/D col=lane&15, row=(lane>>4)*4+reg [m89].
template <int KC, int OUT_BF16>  // KC = K/32
__device__ __forceinline__ void gemm_tile(
        const u16* __restrict__ A, const u16* __restrict__ B,
        const u16* __restrict__ W1, const u16* __restrict__ W2,
        const float* __restrict__ bias,
        float* __restrict__ OutF, int ldo, u16* __restrict__ OutB,
        int n, int relu, int blk) {
    constexpr int K = KC * 32;
    const int lane = threadIdx.x & 63;
    const int wave = threadIdx.x >> 6;
    const int r0 = blk * 64 + wave * 16;
    const int arow = r0 + (lane & 15);
    const size_t abase = (size_t)(arow < n ? arow : n - 1) * K;
    const int kof = (lane >> 4) * 8;

    bf16x8 a1[KC], a2[KC];
#pragma unroll
    for (int kc = 0; kc < KC; kc++) {
        a1[kc] = *(const bf16x8*)&A[abase + kc * 32 + kof];
        a2[kc] = *(const bf16x8*)&B[abase + kc * 32 + kof];
    }
    const int wr = lane & 15;
    const int rbase = r0 + (lane >> 4) * 4;
#pragma unroll
    for (int c = 0; c < 8; c++) {
        f32x4 acc = {0.f, 0.f, 0.f, 0.f};
        const size_t wof = (size_t)(c * 16 + wr) * K + kof;
#pragma unroll
        for (int kc = 0; kc < KC; kc++) {
            acc = __builtin_amdgcn_mfma_f32_16x16x32_bf16(
                a1[kc], *(const bf16x8*)&W1[wof + kc * 32], acc, 0, 0, 0);
            acc = __builtin_amdgcn_mfma_f32_16x16x32_bf16(
                a2[kc], *(const bf16x8*)&W2[wof + kc * 32], acc, 0, 0, 0);
        }
        const int col = c * 16 + wr;
        const float bv = bias[col];
#pragma unroll
        for (int r = 0; r < 4; r++) {
            const int row = rbase + r;
            if (row < n) {
                float v = acc[r] + bv;
                if (relu) v = fmaxf(v, 0.f);
                if (OUT_BF16) {
                    OutB[(size_t)row * 128 + col] = (u16)f2bf(v);
                } else {
                    __builtin_nontemporal_store(v, &OutF[(size_t)row * ldo + col]);
                }
            }
        }
    }
}

// fused L0 gemm: both heads in one dispatch (head = blockIdx.x >= nblk)
__global__ void __launch_bounds__(256) k_gemm_l0_fused(
        const u16* __restrict__ xb,
        const u16* __restrict__ agg0b, const u16* __restrict__ aggUb,
        const u16* __restrict__ Wsb0, const u16* __restrict__ Wnb0,
        const float* __restrict__ b0,
        u16* __restrict__ h1b, u16* __restrict__ u1b, int n, int nblk) {
    const int head = (blockIdx.x >= nblk) ? 1 : 0;
    const int blk = blockIdx.x - head * nblk;
    gemm_tile<2, 1>(xb, head ? aggUb : agg0b,
                    Wsb0 + head * 128 * 64, Wnb0 + head * 128 * 64,
                    b0 + head * 128, (float*)nullptr, 0,
                    head ? u1b : h1b, n, 1, blk);
}

__global__ void __launch_bounds__(256) k_gemm_l1(
        const u16* __restrict__ A, const u16* __restrict__ B,
        const u16* __restrict__ W1, const u16* __restrict__ W2,
        const float* __restrict__ bias, float* __restrict__ OutF, int ldo,
        int n) {
    gemm_tile<4, 0>(A, B, W1, W2, bias, OutF, ldo, (u16*)nullptr, n, 0,
                    blockIdx.x);
}

extern "C" void kernel_launch(void* const* d_in, const int* in_sizes, int n_in,
                              void* d_out, int out_size, void* d_ws, size_t ws_size,
                              hipStream_t stream) {
    const float* x = (const float*)d_in[0];
    const int* src = (const int*)d_in[1];
    const int* dst = (const int*)d_in[2];
    const float* Wn0 = (const float*)d_in[3];
    const float* Ws0 = (const float*)d_in[4];
    const float* b0 = (const float*)d_in[5];
    const float* Wn1 = (const float*)d_in[6];
    const float* Ws1 = (const float*)d_in[7];
    const float* b1 = (const float*)d_in[8];

    const int N = in_sizes[0] / 64;
    const int E = in_sizes[1];
    float* out = (float*)d_out;
    const int NB = (N + 255) >> 8;  // buckets of 256 nodes (must be <= 512)

    // ---- workspace layout ----
    char* w = (char*)d_ws;
    size_t o = 0;
    auto alloc = [&](size_t bytes) -> void* {
        o = (o + 255) & ~(size_t)255;
        void* p = w + o;
        o += bytes;
        return p;
    };
    int* off_in = (int*)alloc((size_t)(N + 1) * 4);
    int* off_out = (int*)alloc((size_t)(N + 1) * 4);
    int* cntD = (int*)alloc(512 * 4);
    int* cntS = (int*)alloc(512 * 4);
    int* curD = (int*)alloc(512 * 4);
    int* curS = (int*)alloc(512 * 4);
    int* bbaseD = (int*)alloc(513 * 4);
    int* bbaseS = (int*)alloc(513 * 4);
    int* adj_in = (int*)alloc((size_t)E * 4);
    int* adj_out = (int*)alloc((size_t)E * 4);
    u16* AGGb = (u16*)alloc((size_t)N * 128 * 2);  // L1 agg; L0 uses as 2x[N][64]
    u16* h1b = (u16*)alloc((size_t)N * 128 * 2);
    u16* u1b = (u16*)alloc((size_t)N * 128 * 2);
    u16* Wsb0 = (u16*)alloc(2 * 128 * 64 * 2);
    u16* Wnb0 = (u16*)alloc(2 * 128 * 64 * 2);
    u16* Wsb1 = (u16*)alloc(2 * 128 * 128 * 2);
    u16* Wnb1 = (u16*)alloc(2 * 128 * 128 * 2);
    (void)ws_size;

    // pair arrays alias h1b/u1b (dead until the L0 gemm runs, after pass D)
    u32* pairsD = (u32*)h1b;
    u32* pairsS = (u32*)u1b;
    // xb (bf16 [N][64]) + xq (fp8 [N][64]) live in d_out scratch
    // (both dead before the final L1 gemms write d_out)
    u16* xb = (u16*)d_out;
    u8* xq = (u8*)d_out + (16 << 20);

    const int n4 = N * 64 / 4;
    const int edgeBlocks = ((E + 7) / 8 + 255) / 256;

    // ---- fused prep: zero cnt + x->bf16+fp8 + weight bf16 conversions ----
    k_prep<<<(n4 + 98304 + 255) / 256, 256, 0, stream>>>(x, xb, xq, n4, cntD,
                                                         Ws0, Wn0, Ws1, Wn1,
                                                         Wsb0, Wnb0, Wsb1, Wnb1);

    // ---- CSR build via bucketed counting sort ----
    k_bincnt<<<edgeBlocks, 256, 0, stream>>>(src, dst, cntD, cntS, E, NB);
    k_binscan<<<1, 512, 0, stream>>>(cntD, cntS, bbaseD, bbaseS, curD, curS,
                                     off_in, off_out, NB, N, E);
    k_binscatter<<<edgeBlocks, 256, 0, stream>>>(src, dst, curD, curS, pairsD, pairsS, E, NB);
    k_bucket_csr<<<2 * NB, 256, 0, stream>>>(pairsD, pairsS, bbaseD, bbaseS,
                                             off_in, adj_in, off_out, adj_out, N);

    const int nodeBlocks = (N + 3) / 4;
    const int gemmBlocks = (N + 63) / 64;

    // ---- layer 0 ----
    u16* agg0b = AGGb;                    // [N][64]
    u16* aggUb = AGGb + (size_t)N * 64;   // [N][64]
    k_agg_l0_q<<<nodeBlocks, 256, 0, stream>>>(xq, off_in, adj_in, off_out, adj_out,
                                               agg0b, aggUb, N);
    k_gemm_l0_fused<<<2 * gemmBlocks, 256, 0, stream>>>(xb, agg0b, aggUb, Wsb0, Wnb0,
                                                        b0, h1b, u1b, N, gemmBlocks);

    // ---- layer 1 ----
    // head0: 'I' -> aggregate h1 over out-edges
    k_agg_l1_b<<<nodeBlocks, 256, 0, stream>>>(h1b, off_out, adj_out, (const int*)nullptr,
                                               (const int*)nullptr, AGGb, N);
    k_gemm_l1<<<gemmBlocks, 256, 0, stream>>>(h1b, AGGb, Wsb1, Wnb1, b1, out, 256, N);
    // head1: 'U' -> aggregate u1 over in+out edges
    k_agg_l1_b<<<nodeBlocks, 256, 0, stream>>>(u1b, off_in, adj_in, off_out, adj_out, AGGb, N);
    k_gemm_l1<<<gemmBlocks, 256, 0, stream>>>(u1b, AGGb, Wsb1 + 128 * 128,
                                              Wnb1 + 128 * 128, b1 + 128, out + 128, 256, N);
}

// Round 8
// 607.645 us; speedup vs baseline: 1.0788x; 1.0788x over previous
//
#include <hip/hip_runtime.h>
#include <hip/hip_fp8.h>

// ---------------------------------------------------------------------------
// SAGEMultiSwitchModel: 2 heads x 2 SAGE layers on N=100k nodes, E=1.6M edges.
// head0 dirs "OI", head1 "UU". Layer: act([h|seg_mean(h)] @ [Ws|Wn]^T + b).
// R1: spill-free gemm. R2: bf16 gather tables. R4: bucketed-sort CSR build.
// R5: MFMA gemms (A-frags in regs, B = untransposed bf16 weights).
// R6: fp8-e4m3 x table for L0 agg (WIN, kept); NT hints (REGRESSION: NT
//     stores evicted producer->consumer handoffs, agg_l1 138->155us).
// R7: revert all NT except the final fp32 output store (write-once data).
// Measured ceiling: random-row gathers pin at ~2.55 TB/s HBM-side miss BW;
// both L1 agg passes sit at it (FETCH 352 MB @ ~138us each).
// ---------------------------------------------------------------------------

typedef unsigned short u16;
typedef unsigned int u32;
typedef unsigned char u8;
typedef __bf16 bf16x8 __attribute__((ext_vector_type(8)));
typedef float f32x4 __attribute__((ext_vector_type(4)));

__device__ __forceinline__ u32 f2bf(float f) {  // RNE float->bf16 (low 16 bits)
    u32 u = __float_as_uint(f);
    return (u + 0x7fffu + ((u >> 16) & 1u)) >> 16;
}
__device__ __forceinline__ float bf_lo(u32 v) { return __uint_as_float(v << 16); }
__device__ __forceinline__ float bf_hi(u32 v) { return __uint_as_float(v & 0xffff0000u); }
__device__ __forceinline__ u8 f2q(float f) {  // float -> fp8 e4m3 (OCP)
    __hip_fp8_e4m3 t(f);
    return *(u8*)&t;
}
__device__ __forceinline__ float q2f(u8 b) {
    __hip_fp8_e4m3 t;
    *(u8*)&t = b;
    return (float)t;
}

// fused prep: zero cnt[1024]; x -> bf16 xb AND fp8 xq; weights -> bf16 flat
__global__ void k_prep(const float* __restrict__ x, u16* __restrict__ xb,
                       u8* __restrict__ xq, int n4, int* __restrict__ cntzero,
                       const float* __restrict__ Ws0, const float* __restrict__ Wn0,
                       const float* __restrict__ Ws1, const float* __restrict__ Wn1,
                       u16* __restrict__ Wsb0, u16* __restrict__ Wnb0,
                       u16* __restrict__ Wsb1, u16* __restrict__ Wnb1) {
    int i = blockIdx.x * blockDim.x + threadIdx.x;
    if (i < 1024) cntzero[i] = 0;
    if (i < n4) {
        float4 v = *(const float4*)&x[(size_t)i * 4];
        u32 p0 = f2bf(v.x) | (f2bf(v.y) << 16);
        u32 p1 = f2bf(v.z) | (f2bf(v.w) << 16);
        *(uint2*)&xb[(size_t)i * 4] = make_uint2(p0, p1);
        u32 q = (u32)f2q(v.x) | ((u32)f2q(v.y) << 8) |
                ((u32)f2q(v.z) << 16) | ((u32)f2q(v.w) << 24);
        *(u32*)&xq[(size_t)i * 4] = q;
        return;
    }
    int t = i - n4;
    if (t < 16384) Wsb0[t] = (u16)f2bf(Ws0[t]);
    else if (t < 32768) Wnb0[t - 16384] = (u16)f2bf(Wn0[t - 16384]);
    else if (t < 65536) Wsb1[t - 32768] = (u16)f2bf(Ws1[t - 32768]);
    else if (t < 98304) Wnb1[t - 65536] = (u16)f2bf(Wn1[t - 65536]);
}

// ---- bucketed CSR build: NPB=256 nodes/bucket, bucket = node>>8 ----

__global__ void __launch_bounds__(256) k_bincnt(
        const int* __restrict__ src, const int* __restrict__ dst,
        int* cntD, int* cntS, int E, int NB) {
    __shared__ int hD[512], hS[512];
    const int tid = threadIdx.x;
    for (int i = tid; i < NB; i += 256) { hD[i] = 0; hS[i] = 0; }
    __syncthreads();
    const int base = (blockIdx.x * 256 + tid) * 8;
#pragma unroll
    for (int i = 0; i < 8; i++) {
        if (base + i < E) {
            atomicAdd(&hD[dst[base + i] >> 8], 1);
            atomicAdd(&hS[src[base + i] >> 8], 1);
        }
    }
    __syncthreads();
    for (int i = tid; i < NB; i += 256) {
        if (hD[i]) atomicAdd(&cntD[i], hD[i]);
        if (hS[i]) atomicAdd(&cntS[i], hS[i]);
    }
}

__global__ void __launch_bounds__(512) k_binscan(
        const int* __restrict__ cntD, const int* __restrict__ cntS,
        int* bbaseD, int* bbaseS, int* curD, int* curS,
        int* off_in, int* off_out, int NB, int N, int E) {
    __shared__ int ts[512];
    const int tid = threadIdx.x;
    int v = (tid < NB) ? cntD[tid] : 0;
    ts[tid] = v;
    __syncthreads();
    for (int ofs = 1; ofs < 512; ofs <<= 1) {
        int t = (tid >= ofs) ? ts[tid - ofs] : 0;
        __syncthreads();
        ts[tid] += t;
        __syncthreads();
    }
    int ex = ts[tid] - v;
    if (tid < NB) { bbaseD[tid] = ex; curD[tid] = ex; }
    if (tid == NB - 1) bbaseD[NB] = ex + v;
    __syncthreads();
    v = (tid < NB) ? cntS[tid] : 0;
    ts[tid] = v;
    __syncthreads();
    for (int ofs = 1; ofs < 512; ofs <<= 1) {
        int t = (tid >= ofs) ? ts[tid - ofs] : 0;
        __syncthreads();
        ts[tid] += t;
        __syncthreads();
    }
    ex = ts[tid] - v;
    if (tid < NB) { bbaseS[tid] = ex; curS[tid] = ex; }
    if (tid == NB - 1) bbaseS[NB] = ex + v;
    if (tid == 0) { off_in[N] = E; off_out[N] = E; }
}

__global__ void __launch_bounds__(256) k_binscatter(
        const int* __restrict__ src, const int* __restrict__ dst,
        int* curD, int* curS, u32* __restrict__ pairsD, u32* __restrict__ pairsS,
        int E, int NB) {
    __shared__ int hD[512], hS[512], bD[512], bS[512];
    const int tid = threadIdx.x;
    for (int i = tid; i < NB; i += 256) { hD[i] = 0; hS[i] = 0; }
    __syncthreads();
    const int base = (blockIdx.x * 256 + tid) * 8;
    int sv[8], dv[8], rD[8], rS[8];
#pragma unroll
    for (int i = 0; i < 8; i++) {
        if (base + i < E) {
            sv[i] = src[base + i];
            dv[i] = dst[base + i];
            rD[i] = atomicAdd(&hD[dv[i] >> 8], 1);
            rS[i] = atomicAdd(&hS[sv[i] >> 8], 1);
        }
    }
    __syncthreads();
    for (int i = tid; i < NB; i += 256) {
        bD[i] = hD[i] ? atomicAdd(&curD[i], hD[i]) : 0;
        bS[i] = hS[i] ? atomicAdd(&curS[i], hS[i]) : 0;
    }
    __syncthreads();
#pragma unroll
    for (int i = 0; i < 8; i++) {
        if (base + i < E) {
            pairsD[bD[dv[i] >> 8] + rD[i]] = ((u32)(dv[i] & 255) << 24) | (u32)sv[i];
            pairsS[bS[sv[i] >> 8] + rS[i]] = ((u32)(sv[i] & 255) << 24) | (u32)dv[i];
        }
    }
}

__global__ void __launch_bounds__(256) k_bucket_csr(
        const u32* __restrict__ pairsD, const u32* __restrict__ pairsS,
        const int* __restrict__ bbaseD, const int* __restrict__ bbaseS,
        int* __restrict__ off_in, int* __restrict__ adj_in,
        int* __restrict__ off_out, int* __restrict__ adj_out, int N) {
    __shared__ int cnt[256], cur[256], ts[256];
    const int b = blockIdx.x >> 1;
    const int arr = blockIdx.x & 1;
    const u32* pairs = arr ? pairsS : pairsD;
    const int* bbase = arr ? bbaseS : bbaseD;
    int* off = arr ? off_out : off_in;
    int* adj = arr ? adj_out : adj_in;
    const int e0 = bbase[b], e1 = bbase[b + 1];
    const int tid = threadIdx.x;
    cnt[tid] = 0;
    __syncthreads();
    for (int e = e0 + tid; e < e1; e += 256) atomicAdd(&cnt[pairs[e] >> 24], 1);
    __syncthreads();
    int v = cnt[tid];
    ts[tid] = v;
    __syncthreads();
    for (int ofs = 1; ofs < 256; ofs <<= 1) {
        int t = (tid >= ofs) ? ts[tid - ofs] : 0;
        __syncthreads();
        ts[tid] += t;
        __syncthreads();
    }
    const int ex = ts[tid] - v;
    const int n = b * 256 + tid;
    if (n < N) off[n] = e0 + ex;
    cur[tid] = e0 + ex;
    __syncthreads();
    for (int e = e0 + tid; e < e1; e += 256) {
        u32 p = pairs[e];
        int w = atomicAdd(&cur[p >> 24], 1);
        adj[w] = (int)(p & 0xFFFFFFu);
    }
}

// layer-0 aggregation: F=64 fp8 gather (1 byte/lane, 64B/row), x8 unrolled.
__global__ void __launch_bounds__(256) k_agg_l0_q(
        const u8* __restrict__ xq,
        const int* __restrict__ off_in, const int* __restrict__ adj_in,
        const int* __restrict__ off_out, const int* __restrict__ adj_out,
        u16* __restrict__ agg0b, u16* __restrict__ aggUb, int n) {
    const int node = blockIdx.x * 4 + (threadIdx.x >> 6);
    const int lane = threadIdx.x & 63;
    if (node >= n) return;
    const int a0 = off_in[node], a1 = off_in[node + 1];
    const int b0 = off_out[node], b1 = off_out[node + 1];
    float sin_ = 0.f, sout_ = 0.f;
    int j = a0;
    for (; j + 7 < a1; j += 8) {
        int i0 = adj_in[j], i1 = adj_in[j + 1], i2 = adj_in[j + 2], i3 = adj_in[j + 3];
        int i4 = adj_in[j + 4], i5 = adj_in[j + 5], i6 = adj_in[j + 6], i7 = adj_in[j + 7];
        float v0 = q2f(xq[(size_t)i0 * 64 + lane]);
        float v1 = q2f(xq[(size_t)i1 * 64 + lane]);
        float v2 = q2f(xq[(size_t)i2 * 64 + lane]);
        float v3 = q2f(xq[(size_t)i3 * 64 + lane]);
        float v4 = q2f(xq[(size_t)i4 * 64 + lane]);
        float v5 = q2f(xq[(size_t)i5 * 64 + lane]);
        float v6 = q2f(xq[(size_t)i6 * 64 + lane]);
        float v7 = q2f(xq[(size_t)i7 * 64 + lane]);
        sin_ += ((v0 + v1) + (v2 + v3)) + ((v4 + v5) + (v6 + v7));
    }
    for (; j < a1; j++) sin_ += q2f(xq[(size_t)adj_in[j] * 64 + lane]);
    j = b0;
    for (; j + 7 < b1; j += 8) {
        int i0 = adj_out[j], i1 = adj_out[j + 1], i2 = adj_out[j + 2], i3 = adj_out[j + 3];
        int i4 = adj_out[j + 4], i5 = adj_out[j + 5], i6 = adj_out[j + 6], i7 = adj_out[j + 7];
        float v0 = q2f(xq[(size_t)i0 * 64 + lane]);
        float v1 = q2f(xq[(size_t)i1 * 64 + lane]);
        float v2 = q2f(xq[(size_t)i2 * 64 + lane]);
        float v3 = q2f(xq[(size_t)i3 * 64 + lane]);
        float v4 = q2f(xq[(size_t)i4 * 64 + lane]);
        float v5 = q2f(xq[(size_t)i5 * 64 + lane]);
        float v6 = q2f(xq[(size_t)i6 * 64 + lane]);
        float v7 = q2f(xq[(size_t)i7 * 64 + lane]);
        sout_ += ((v0 + v1) + (v2 + v3)) + ((v4 + v5) + (v6 + v7));
    }
    for (; j < b1; j++) sout_ += q2f(xq[(size_t)adj_out[j] * 64 + lane]);
    const int din = a1 - a0, dout = b1 - b0;
    const int du = din + dout;
    agg0b[(size_t)node * 64 + lane] = (u16)f2bf(din ? sin_ / (float)din : 0.f);
    aggUb[(size_t)node * 64 + lane] = (u16)f2bf(du ? (sin_ + sout_) / (float)du : 0.f);
}

// layer-1 aggregation: F=128 bf16 gather (lane reads packed u32 pair), x8.
__global__ void __launch_bounds__(256) k_agg_l1_b(
        const u16* __restrict__ Hb,
        const int* __restrict__ offA, const int* __restrict__ adjA,
        const int* __restrict__ offB, const int* __restrict__ adjB,
        u16* __restrict__ outb, int n) {
    const int node = blockIdx.x * 4 + (threadIdx.x >> 6);
    const int lane = threadIdx.x & 63;
    if (node >= n) return;
    float s0 = 0.f, s1 = 0.f;
    const int a0 = offA[node], a1 = offA[node + 1];
    int j = a0;
    for (; j + 7 < a1; j += 8) {
        int i0 = adjA[j], i1 = adjA[j + 1], i2 = adjA[j + 2], i3 = adjA[j + 3];
        int i4 = adjA[j + 4], i5 = adjA[j + 5], i6 = adjA[j + 6], i7 = adjA[j + 7];
        u32 v0 = *(const u32*)&Hb[(size_t)i0 * 128 + lane * 2];
        u32 v1 = *(const u32*)&Hb[(size_t)i1 * 128 + lane * 2];
        u32 v2 = *(const u32*)&Hb[(size_t)i2 * 128 + lane * 2];
        u32 v3 = *(const u32*)&Hb[(size_t)i3 * 128 + lane * 2];
        u32 v4 = *(const u32*)&Hb[(size_t)i4 * 128 + lane * 2];
        u32 v5 = *(const u32*)&Hb[(size_t)i5 * 128 + lane * 2];
        u32 v6 = *(const u32*)&Hb[(size_t)i6 * 128 + lane * 2];
        u32 v7 = *(const u32*)&Hb[(size_t)i7 * 128 + lane * 2];
        s0 += ((bf_lo(v0) + bf_lo(v1)) + (bf_lo(v2) + bf_lo(v3))) +
              ((bf_lo(v4) + bf_lo(v5)) + (bf_lo(v6) + bf_lo(v7)));
        s1 += ((bf_hi(v0) + bf_hi(v1)) + (bf_hi(v2) + bf_hi(v3))) +
              ((bf_hi(v4) + bf_hi(v5)) + (bf_hi(v6) + bf_hi(v7)));
    }
    for (; j < a1; j++) {
        u32 v = *(const u32*)&Hb[(size_t)adjA[j] * 128 + lane * 2];
        s0 += bf_lo(v);
        s1 += bf_hi(v);
    }
    int deg = a1 - a0;
    if (offB) {
        const int b0 = offB[node], b1 = offB[node + 1];
        j = b0;
        for (; j + 7 < b1; j += 8) {
            int i0 = adjB[j], i1 = adjB[j + 1], i2 = adjB[j + 2], i3 = adjB[j + 3];
            int i4 = adjB[j + 4], i5 = adjB[j + 5], i6 = adjB[j + 6], i7 = adjB[j + 7];
            u32 v0 = *(const u32*)&Hb[(size_t)i0 * 128 + lane * 2];
            u32 v1 = *(const u32*)&Hb[(size_t)i1 * 128 + lane * 2];
            u32 v2 = *(const u32*)&Hb[(size_t)i2 * 128 + lane * 2];
            u32 v3 = *(const u32*)&Hb[(size_t)i3 * 128 + lane * 2];
            u32 v4 = *(const u32*)&Hb[(size_t)i4 * 128 + lane * 2];
            u32 v5 = *(const u32*)&Hb[(size_t)i5 * 128 + lane * 2];
            u32 v6 = *(const u32*)&Hb[(size_t)i6 * 128 + lane * 2];
            u32 v7 = *(const u32*)&Hb[(size_t)i7 * 128 + lane * 2];
            s0 += ((bf_lo(v0) + bf_lo(v1)) + (bf_lo(v2) + bf_lo(v3))) +
                  ((bf_lo(v4) + bf_lo(v5)) + (bf_lo(v6) + bf_lo(v7)));
            s1 += ((bf_hi(v0) + bf_hi(v1)) + (bf_hi(v2) + bf_hi(v3))) +
                  ((bf_hi(v4) + bf_hi(v5)) + (bf_hi(v6) + bf_hi(v7)));
        }
        for (; j < b1; j++) {
            u32 v = *(const u32*)&Hb[(size_t)adjB[j] * 128 + lane * 2];
            s0 += bf_lo(v);
            s1 += bf_hi(v);
        }
        deg += b1 - b0;
    }
    float inv = deg ? 1.f / (float)deg : 0.f;
    u32 p = f2bf(s0 * inv) | (f2bf(s1 * inv) << 16);
    *(u32*)&outb[(size_t)node * 128 + lane * 2] = p;
}

// MFMA dual-GEMM tile body: 16 rows x 128 cols per wave, A-frags in regs,
// B-frags read directly from untransposed bf16 weights [128][K].
// Layouts (gfx950 16x16x32 bf16): A row=lane&15, k=8*(lane>>4)+j; B col=lane&15;
// C/D col=lane&15, row=(lane>>4)*4+reg [m89].
// NT store ONLY on the final fp32 output (write-once, never re-read on GPU).
template <int KC, int OUT_BF16>  // KC = K/32
__device__ __forceinline__ void gemm_tile(
        const u16* __restrict__ A, const u16* __restrict__ B,
        const u16* __restrict__ W1, const u16* __restrict__ W2,
        const float* __restrict__ bias,
        float* __restrict__ OutF, int ldo, u16* __restrict__ OutB,
        int n, int relu, int blk) {
    constexpr int K = KC * 32;
    const int lane = threadIdx.x & 63;
    const int wave = threadIdx.x >> 6;
    const int r0 = blk * 64 + wave * 16;
    const int arow = r0 + (lane & 15);
    const size_t abase = (size_t)(arow < n ? arow : n - 1) * K;
    const int kof = (lane >> 4) * 8;

    bf16x8 a1[KC], a2[KC];
#pragma unroll
    for (int kc = 0; kc < KC; kc++) {
        a1[kc] = *(const bf16x8*)&A[abase + kc * 32 + kof];
        a2[kc] = *(const bf16x8*)&B[abase + kc * 32 + kof];
    }
    const int wr = lane & 15;
    const int rbase = r0 + (lane >> 4) * 4;
#pragma unroll
    for (int c = 0; c < 8; c++) {
        f32x4 acc = {0.f, 0.f, 0.f, 0.f};
        const size_t wof = (size_t)(c * 16 + wr) * K + kof;
#pragma unroll
        for (int kc = 0; kc < KC; kc++) {
            acc = __builtin_amdgcn_mfma_f32_16x16x32_bf16(
                a1[kc], *(const bf16x8*)&W1[wof + kc * 32], acc, 0, 0, 0);
            acc = __builtin_amdgcn_mfma_f32_16x16x32_bf16(
                a2[kc], *(const bf16x8*)&W2[wof + kc * 32], acc, 0, 0, 0);
        }
        const int col = c * 16 + wr;
        const float bv = bias[col];
#pragma unroll
        for (int r = 0; r < 4; r++) {
            const int row = rbase + r;
            if (row < n) {
                float v = acc[r] + bv;
                if (relu) v = fmaxf(v, 0.f);
                if (OUT_BF16) {
                    OutB[(size_t)row * 128 + col] = (u16)f2bf(v);
                } else {
                    __builtin_nontemporal_store(v, &OutF[(size_t)row * ldo + col]);
                }
            }
        }
    }
}

// fused L0 gemm: both heads in one dispatch (head = blockIdx.x >= nblk)
__global__ void __launch_bounds__(256) k_gemm_l0_fused(
        const u16* __restrict__ xb,
        const u16* __restrict__ agg0b, const u16* __restrict__ aggUb,
        const u16* __restrict__ Wsb0, const u16* __restrict__ Wnb0,
        const float* __restrict__ b0,
        u16* __restrict__ h1b, u16* __restrict__ u1b, int n, int nblk) {
    const int head = (blockIdx.x >= nblk) ? 1 : 0;
    const int blk = blockIdx.x - head * nblk;
    gemm_tile<2, 1>(xb, head ? aggUb : agg0b,
                    Wsb0 + head * 128 * 64, Wnb0 + head * 128 * 64,
                    b0 + head * 128, (float*)nullptr, 0,
                    head ? u1b : h1b, n, 1, blk);
}

__global__ void __launch_bounds__(256) k_gemm_l1(
        const u16* __restrict__ A, const u16* __restrict__ B,
        const u16* __restrict__ W1, const u16* __restrict__ W2,
        const float* __restrict__ bias, float* __restrict__ OutF, int ldo,
        int n) {
    gemm_tile<4, 0>(A, B, W1, W2, bias, OutF, ldo, (u16*)nullptr, n, 0,
                    blockIdx.x);
}

extern "C" void kernel_launch(void* const* d_in, const int* in_sizes, int n_in,
                              void* d_out, int out_size, void* d_ws, size_t ws_size,
                              hipStream_t stream) {
    const float* x = (const float*)d_in[0];
    const int* src = (const int*)d_in[1];
    const int* dst = (const int*)d_in[2];
    const float* Wn0 = (const float*)d_in[3];
    const float* Ws0 = (const float*)d_in[4];
    const float* b0 = (const float*)d_in[5];
    const float* Wn1 = (const float*)d_in[6];
    const float* Ws1 = (const float*)d_in[7];
    const float* b1 = (const float*)d_in[8];

    const int N = in_sizes[0] / 64;
    const int E = in_sizes[1];
    float* out = (float*)d_out;
    const int NB = (N + 255) >> 8;  // buckets of 256 nodes (must be <= 512)

    // ---- workspace layout ----
    char* w = (char*)d_ws;
    size_t o = 0;
    auto alloc = [&](size_t bytes) -> void* {
        o = (o + 255) & ~(size_t)255;
        void* p = w + o;
        o += bytes;
        return p;
    };
    int* off_in = (int*)alloc((size_t)(N + 1) * 4);
    int* off_out = (int*)alloc((size_t)(N + 1) * 4);
    int* cntD = (int*)alloc(512 * 4);
    int* cntS = (int*)alloc(512 * 4);
    int* curD = (int*)alloc(512 * 4);
    int* curS = (int*)alloc(512 * 4);
    int* bbaseD = (int*)alloc(513 * 4);
    int* bbaseS = (int*)alloc(513 * 4);
    int* adj_in = (int*)alloc((size_t)E * 4);
    int* adj_out = (int*)alloc((size_t)E * 4);
    u16* AGGb = (u16*)alloc((size_t)N * 128 * 2);  // L1 agg; L0 uses as 2x[N][64]
    u16* h1b = (u16*)alloc((size_t)N * 128 * 2);
    u16* u1b = (u16*)alloc((size_t)N * 128 * 2);
    u16* Wsb0 = (u16*)alloc(2 * 128 * 64 * 2);
    u16* Wnb0 = (u16*)alloc(2 * 128 * 64 * 2);
    u16* Wsb1 = (u16*)alloc(2 * 128 * 128 * 2);
    u16* Wnb1 = (u16*)alloc(2 * 128 * 128 * 2);
    (void)ws_size;

    // pair arrays alias h1b/u1b (dead until the L0 gemm runs, after pass D)
    u32* pairsD = (u32*)h1b;
    u32* pairsS = (u32*)u1b;
    // xb (bf16 [N][64]) + xq (fp8 [N][64]) live in d_out scratch
    // (both dead before the final L1 gemms write d_out)
    u16* xb = (u16*)d_out;
    u8* xq = (u8*)d_out + (16 << 20);

    const int n4 = N * 64 / 4;
    const int edgeBlocks = ((E + 7) / 8 + 255) / 256;

    // ---- fused prep: zero cnt + x->bf16+fp8 + weight bf16 conversions ----
    k_prep<<<(n4 + 98304 + 255) / 256, 256, 0, stream>>>(x, xb, xq, n4, cntD,
                                                         Ws0, Wn0, Ws1, Wn1,
                                                         Wsb0, Wnb0, Wsb1, Wnb1);

    // ---- CSR build via bucketed counting sort ----
    k_bincnt<<<edgeBlocks, 256, 0, stream>>>(src, dst, cntD, cntS, E, NB);
    k_binscan<<<1, 512, 0, stream>>>(cntD, cntS, bbaseD, bbaseS, curD, curS,
                                     off_in, off_out, NB, N, E);
    k_binscatter<<<edgeBlocks, 256, 0, stream>>>(src, dst, curD, curS, pairsD, pairsS, E, NB);
    k_bucket_csr<<<2 * NB, 256, 0, stream>>>(pairsD, pairsS, bbaseD, bbaseS,
                                             off_in, adj_in, off_out, adj_out, N);

    const int nodeBlocks = (N + 3) / 4;
    const int gemmBlocks = (N + 63) / 64;

    // ---- layer 0 ----
    u16* agg0b = AGGb;                    // [N][64]
    u16* aggUb = AGGb + (size_t)N * 64;   // [N][64]
    k_agg_l0_q<<<nodeBlocks, 256, 0, stream>>>(xq, off_in, adj_in, off_out, adj_out,
                                               agg0b, aggUb, N);
    k_gemm_l0_fused<<<2 * gemmBlocks, 256, 0, stream>>>(xb, agg0b, aggUb, Wsb0, Wnb0,
                                                        b0, h1b, u1b, N, gemmBlocks);

    // ---- layer 1 ----
    // head0: 'I' -> aggregate h1 over out-edges
    k_agg_l1_b<<<nodeBlocks, 256, 0, stream>>>(h1b, off_out, adj_out, (const int*)nullptr,
                                               (const int*)nullptr, AGGb, N);
    k_gemm_l1<<<gemmBlocks, 256, 0, stream>>>(h1b, AGGb, Wsb1, Wnb1, b1, out, 256, N);
    // head1: 'U' -> aggregate u1 over in+out edges
    k_agg_l1_b<<<nodeBlocks, 256, 0, stream>>>(u1b, off_in, adj_in, off_out, adj_out, AGGb, N);
    k_gemm_l1<<<gemmBlocks, 256, 0, stream>>>(u1b, AGGb, Wsb1 + 128 * 128,
                                              Wnb1 + 128 * 128, b1 + 128, out + 128, 256, N);
}

// Round 9
// 580.725 us; speedup vs baseline: 1.1288x; 1.0464x over previous
//
#include <hip/hip_runtime.h>
#include <hip/hip_fp8.h>

// ---------------------------------------------------------------------------
// SAGEMultiSwitchModel: 2 heads x 2 SAGE layers on N=100k nodes, E=1.6M edges.
// head0 dirs "OI", head1 "UU". Layer: act([h|seg_mean(h)] @ [Ws|Wn]^T + b).
// R1: spill-free gemm. R2: bf16 gather tables. R4: bucketed-sort CSR build.
// R5: MFMA gemms. R6: fp8 x-table for L0 agg. R7: NT only on final store.
// R8 finding: I-pass (410MB req) and U-pass (819MB req) BOTH fetch 352MB in
//     138us -> miss-BW-bound at ~2.55 TB/s. Lever = miss bytes.
// R9: per-feature-scaled uint8 L1 gather tables (post-relu >=0; sigma ~4x
//     tighter than fp8) + integer-sum aggregation (scale factored out) +
//     single fused L1 agg pass. int8 tables & agg outputs live time-phased
//     in d_out (strided per-row slots); no workspace growth.
//     d_out row r (1024B): [0,128)=h1q [128,256)=u1q [512,768)=aggH
//     [768,1024)=aggU -> gemm1 writes [0,512), gemm2 writes [512,1024)
//     (same-wave read-before-write; frags in regs before stores).
// ---------------------------------------------------------------------------

typedef unsigned short u16;
typedef unsigned int u32;
typedef unsigned char u8;
typedef __bf16 bf16x8 __attribute__((ext_vector_type(8)));
typedef float f32x4 __attribute__((ext_vector_type(4)));

__device__ __forceinline__ u32 f2bf(float f) {  // RNE float->bf16 (low 16 bits)
    u32 u = __float_as_uint(f);
    return (u + 0x7fffu + ((u >> 16) & 1u)) >> 16;
}
__device__ __forceinline__ float bf_lo(u32 v) { return __uint_as_float(v << 16); }
__device__ __forceinline__ float bf_hi(u32 v) { return __uint_as_float(v & 0xffff0000u); }
__device__ __forceinline__ u8 f2q(float f) {  // float -> fp8 e4m3 (OCP)
    __hip_fp8_e4m3 t(f);
    return *(u8*)&t;
}
__device__ __forceinline__ float q2f(u8 b) {
    __hip_fp8_e4m3 t;
    *(u8*)&t = b;
    return (float)t;
}

// fused prep: zero cnt[1024]+maxs[256]; x -> bf16 xb AND fp8 xq; weights bf16
__global__ void k_prep(const float* __restrict__ x, u16* __restrict__ xb,
                       u8* __restrict__ xq, int n4, int* __restrict__ cntzero,
                       int* __restrict__ maxzero,
                       const float* __restrict__ Ws0, const float* __restrict__ Wn0,
                       const float* __restrict__ Ws1, const float* __restrict__ Wn1,
                       u16* __restrict__ Wsb0, u16* __restrict__ Wnb0,
                       u16* __restrict__ Wsb1, u16* __restrict__ Wnb1) {
    int i = blockIdx.x * blockDim.x + threadIdx.x;
    if (i < 1024) cntzero[i] = 0;
    if (i < 256) maxzero[i] = 0;
    if (i < n4) {
        float4 v = *(const float4*)&x[(size_t)i * 4];
        u32 p0 = f2bf(v.x) | (f2bf(v.y) << 16);
        u32 p1 = f2bf(v.z) | (f2bf(v.w) << 16);
        *(uint2*)&xb[(size_t)i * 4] = make_uint2(p0, p1);
        u32 q = (u32)f2q(v.x) | ((u32)f2q(v.y) << 8) |
                ((u32)f2q(v.z) << 16) | ((u32)f2q(v.w) << 24);
        *(u32*)&xq[(size_t)i * 4] = q;
        return;
    }
    int t = i - n4;
    if (t < 16384) Wsb0[t] = (u16)f2bf(Ws0[t]);
    else if (t < 32768) Wnb0[t - 16384] = (u16)f2bf(Wn0[t - 16384]);
    else if (t < 65536) Wsb1[t - 32768] = (u16)f2bf(Ws1[t - 32768]);
    else if (t < 98304) Wnb1[t - 65536] = (u16)f2bf(Wn1[t - 65536]);
}

// ---- bucketed CSR build: NPB=256 nodes/bucket, bucket = node>>8 ----

__global__ void __launch_bounds__(256) k_bincnt(
        const int* __restrict__ src, const int* __restrict__ dst,
        int* cntD, int* cntS, int E, int NB) {
    __shared__ int hD[512], hS[512];
    const int tid = threadIdx.x;
    for (int i = tid; i < NB; i += 256) { hD[i] = 0; hS[i] = 0; }
    __syncthreads();
    const int base = (blockIdx.x * 256 + tid) * 8;
#pragma unroll
    for (int i = 0; i < 8; i++) {
        if (base + i < E) {
            atomicAdd(&hD[dst[base + i] >> 8], 1);
            atomicAdd(&hS[src[base + i] >> 8], 1);
        }
    }
    __syncthreads();
    for (int i = tid; i < NB; i += 256) {
        if (hD[i]) atomicAdd(&cntD[i], hD[i]);
        if (hS[i]) atomicAdd(&cntS[i], hS[i]);
    }
}

__global__ void __launch_bounds__(512) k_binscan(
        const int* __restrict__ cntD, const int* __restrict__ cntS,
        int* bbaseD, int* bbaseS, int* curD, int* curS,
        int* off_in, int* off_out, int NB, int N, int E) {
    __shared__ int ts[512];
    const int tid = threadIdx.x;
    int v = (tid < NB) ? cntD[tid] : 0;
    ts[tid] = v;
    __syncthreads();
    for (int ofs = 1; ofs < 512; ofs <<= 1) {
        int t = (tid >= ofs) ? ts[tid - ofs] : 0;
        __syncthreads();
        ts[tid] += t;
        __syncthreads();
    }
    int ex = ts[tid] - v;
    if (tid < NB) { bbaseD[tid] = ex; curD[tid] = ex; }
    if (tid == NB - 1) bbaseD[NB] = ex + v;
    __syncthreads();
    v = (tid < NB) ? cntS[tid] : 0;
    ts[tid] = v;
    __syncthreads();
    for (int ofs = 1; ofs < 512; ofs <<= 1) {
        int t = (tid >= ofs) ? ts[tid - ofs] : 0;
        __syncthreads();
        ts[tid] += t;
        __syncthreads();
    }
    ex = ts[tid] - v;
    if (tid < NB) { bbaseS[tid] = ex; curS[tid] = ex; }
    if (tid == NB - 1) bbaseS[NB] = ex + v;
    if (tid == 0) { off_in[N] = E; off_out[N] = E; }
}

__global__ void __launch_bounds__(256) k_binscatter(
        const int* __restrict__ src, const int* __restrict__ dst,
        int* curD, int* curS, u32* __restrict__ pairsD, u32* __restrict__ pairsS,
        int E, int NB) {
    __shared__ int hD[512], hS[512], bD[512], bS[512];
    const int tid = threadIdx.x;
    for (int i = tid; i < NB; i += 256) { hD[i] = 0; hS[i] = 0; }
    __syncthreads();
    const int base = (blockIdx.x * 256 + tid) * 8;
    int sv[8], dv[8], rD[8], rS[8];
#pragma unroll
    for (int i = 0; i < 8; i++) {
        if (base + i < E) {
            sv[i] = src[base + i];
            dv[i] = dst[base + i];
            rD[i] = atomicAdd(&hD[dv[i] >> 8], 1);
            rS[i] = atomicAdd(&hS[sv[i] >> 8], 1);
        }
    }
    __syncthreads();
    for (int i = tid; i < NB; i += 256) {
        bD[i] = hD[i] ? atomicAdd(&curD[i], hD[i]) : 0;
        bS[i] = hS[i] ? atomicAdd(&curS[i], hS[i]) : 0;
    }
    __syncthreads();
#pragma unroll
    for (int i = 0; i < 8; i++) {
        if (base + i < E) {
            pairsD[bD[dv[i] >> 8] + rD[i]] = ((u32)(dv[i] & 255) << 24) | (u32)sv[i];
            pairsS[bS[sv[i] >> 8] + rS[i]] = ((u32)(sv[i] & 255) << 24) | (u32)dv[i];
        }
    }
}

__global__ void __launch_bounds__(256) k_bucket_csr(
        const u32* __restrict__ pairsD, const u32* __restrict__ pairsS,
        const int* __restrict__ bbaseD, const int* __restrict__ bbaseS,
        int* __restrict__ off_in, int* __restrict__ adj_in,
        int* __restrict__ off_out, int* __restrict__ adj_out, int N) {
    __shared__ int cnt[256], cur[256], ts[256];
    const int b = blockIdx.x >> 1;
    const int arr = blockIdx.x & 1;
    const u32* pairs = arr ? pairsS : pairsD;
    const int* bbase = arr ? bbaseS : bbaseD;
    int* off = arr ? off_out : off_in;
    int* adj = arr ? adj_out : adj_in;
    const int e0 = bbase[b], e1 = bbase[b + 1];
    const int tid = threadIdx.x;
    cnt[tid] = 0;
    __syncthreads();
    for (int e = e0 + tid; e < e1; e += 256) atomicAdd(&cnt[pairs[e] >> 24], 1);
    __syncthreads();
    int v = cnt[tid];
    ts[tid] = v;
    __syncthreads();
    for (int ofs = 1; ofs < 256; ofs <<= 1) {
        int t = (tid >= ofs) ? ts[tid - ofs] : 0;
        __syncthreads();
        ts[tid] += t;
        __syncthreads();
    }
    const int ex = ts[tid] - v;
    const int n = b * 256 + tid;
    if (n < N) off[n] = e0 + ex;
    cur[tid] = e0 + ex;
    __syncthreads();
    for (int e = e0 + tid; e < e1; e += 256) {
        u32 p = pairs[e];
        int w = atomicAdd(&cur[p >> 24], 1);
        adj[w] = (int)(p & 0xFFFFFFu);
    }
}

// layer-0 aggregation: F=64 fp8 gather (1 byte/lane, 64B/row), x8 unrolled.
__global__ void __launch_bounds__(256) k_agg_l0_q(
        const u8* __restrict__ xq,
        const int* __restrict__ off_in, const int* __restrict__ adj_in,
        const int* __restrict__ off_out, const int* __restrict__ adj_out,
        u16* __restrict__ agg0b, u16* __restrict__ aggUb, int n) {
    const int node = blockIdx.x * 4 + (threadIdx.x >> 6);
    const int lane = threadIdx.x & 63;
    if (node >= n) return;
    const int a0 = off_in[node], a1 = off_in[node + 1];
    const int b0 = off_out[node], b1 = off_out[node + 1];
    float sin_ = 0.f, sout_ = 0.f;
    int j = a0;
    for (; j + 7 < a1; j += 8) {
        int i0 = adj_in[j], i1 = adj_in[j + 1], i2 = adj_in[j + 2], i3 = adj_in[j + 3];
        int i4 = adj_in[j + 4], i5 = adj_in[j + 5], i6 = adj_in[j + 6], i7 = adj_in[j + 7];
        float v0 = q2f(xq[(size_t)i0 * 64 + lane]);
        float v1 = q2f(xq[(size_t)i1 * 64 + lane]);
        float v2 = q2f(xq[(size_t)i2 * 64 + lane]);
        float v3 = q2f(xq[(size_t)i3 * 64 + lane]);
        float v4 = q2f(xq[(size_t)i4 * 64 + lane]);
        float v5 = q2f(xq[(size_t)i5 * 64 + lane]);
        float v6 = q2f(xq[(size_t)i6 * 64 + lane]);
        float v7 = q2f(xq[(size_t)i7 * 64 + lane]);
        sin_ += ((v0 + v1) + (v2 + v3)) + ((v4 + v5) + (v6 + v7));
    }
    for (; j < a1; j++) sin_ += q2f(xq[(size_t)adj_in[j] * 64 + lane]);
    j = b0;
    for (; j + 7 < b1; j += 8) {
        int i0 = adj_out[j], i1 = adj_out[j + 1], i2 = adj_out[j + 2], i3 = adj_out[j + 3];
        int i4 = adj_out[j + 4], i5 = adj_out[j + 5], i6 = adj_out[j + 6], i7 = adj_out[j + 7];
        float v0 = q2f(xq[(size_t)i0 * 64 + lane]);
        float v1 = q2f(xq[(size_t)i1 * 64 + lane]);
        float v2 = q2f(xq[(size_t)i2 * 64 + lane]);
        float v3 = q2f(xq[(size_t)i3 * 64 + lane]);
        float v4 = q2f(xq[(size_t)i4 * 64 + lane]);
        float v5 = q2f(xq[(size_t)i5 * 64 + lane]);
        float v6 = q2f(xq[(size_t)i6 * 64 + lane]);
        float v7 = q2f(xq[(size_t)i7 * 64 + lane]);
        sout_ += ((v0 + v1) + (v2 + v3)) + ((v4 + v5) + (v6 + v7));
    }
    for (; j < b1; j++) sout_ += q2f(xq[(size_t)adj_out[j] * 64 + lane]);
    const int din = a1 - a0, dout = b1 - b0;
    const int du = din + dout;
    agg0b[(size_t)node * 64 + lane] = (u16)f2bf(din ? sin_ / (float)din : 0.f);
    aggUb[(size_t)node * 64 + lane] = (u16)f2bf(du ? (sin_ + sout_) / (float)du : 0.f);
}

// quantize h1b/u1b (bf16 [N][128]) -> uint8 per-feature-scaled, into d_out
// strided slots: row r bytes [1024r + head*128, +128).
__global__ void __launch_bounds__(256) k_quant(
        const u16* __restrict__ h1b, const u16* __restrict__ u1b,
        const float* __restrict__ maxH, const float* __restrict__ maxU,
        u8* __restrict__ ob, int N) {
    int i = blockIdx.x * blockDim.x + threadIdx.x;  // 8 elems/thread
    const int total = N * 16;
    if (i >= 2 * total) return;
    const int head = (i >= total) ? 1 : 0;
    int t = i - head * total;
    const int row = t >> 4, seg = t & 15;
    const u16* src = head ? u1b : h1b;
    const float* mx = head ? maxU : maxH;
    uint4 v = *(const uint4*)&src[(size_t)row * 128 + seg * 8];
    float4 m0 = *(const float4*)&mx[seg * 8];
    float4 m1 = *(const float4*)&mx[seg * 8 + 4];
    float rs0 = m0.x > 0.f ? 255.f / m0.x : 0.f;
    float rs1 = m0.y > 0.f ? 255.f / m0.y : 0.f;
    float rs2 = m0.z > 0.f ? 255.f / m0.z : 0.f;
    float rs3 = m0.w > 0.f ? 255.f / m0.w : 0.f;
    float rs4 = m1.x > 0.f ? 255.f / m1.x : 0.f;
    float rs5 = m1.y > 0.f ? 255.f / m1.y : 0.f;
    float rs6 = m1.z > 0.f ? 255.f / m1.z : 0.f;
    float rs7 = m1.w > 0.f ? 255.f / m1.w : 0.f;
    u32 q0 = (u32)fminf(rintf(bf_lo(v.x) * rs0), 255.f);
    u32 q1 = (u32)fminf(rintf(bf_hi(v.x) * rs1), 255.f);
    u32 q2 = (u32)fminf(rintf(bf_lo(v.y) * rs2), 255.f);
    u32 q3 = (u32)fminf(rintf(bf_hi(v.y) * rs3), 255.f);
    u32 q4 = (u32)fminf(rintf(bf_lo(v.z) * rs4), 255.f);
    u32 q5 = (u32)fminf(rintf(bf_hi(v.z) * rs5), 255.f);
    u32 q6 = (u32)fminf(rintf(bf_lo(v.w) * rs6), 255.f);
    u32 q7 = (u32)fminf(rintf(bf_hi(v.w) * rs7), 255.f);
    uint2 p;
    p.x = q0 | (q1 << 8) | (q2 << 16) | (q3 << 24);
    p.y = q4 | (q5 << 8) | (q6 << 16) | (q7 << 24);
    *(uint2*)(ob + ((size_t)row << 10) + head * 128 + seg * 8) = p;
}

// fused L1 aggregation: per node, out-adj gathers h1q AND u1q (shared idx),
// in-adj gathers u1q. Integer sums; scale applied once. Gather rows: 128B
// uint8 at byte 1024*idx (+128 for u1q). Outputs bf16 aggH/aggU at row
// bytes +512 / +768. x8 unrolled.
__global__ void __launch_bounds__(256) k_agg_l1_f(
        const u8* __restrict__ ob,
        const int* __restrict__ off_in, const int* __restrict__ adj_in,
        const int* __restrict__ off_out, const int* __restrict__ adj_out,
        const float* __restrict__ maxH, const float* __restrict__ maxU, int n) {
    const int node = blockIdx.x * 4 + (threadIdx.x >> 6);
    const int lane = threadIdx.x & 63;
    if (node >= n) return;
    const int a0 = off_out[node], a1 = off_out[node + 1];  // out-adj: h1 + u1
    const int b0 = off_in[node], b1 = off_in[node + 1];    // in-adj: u1 only
    u32 sH0 = 0, sH1 = 0, sU0 = 0, sU1 = 0;
    const int lo2 = lane * 2;
    int j = a0;
    for (; j + 7 < a1; j += 8) {
        size_t p0 = ((size_t)adj_out[j] << 10) + lo2;
        size_t p1 = ((size_t)adj_out[j + 1] << 10) + lo2;
        size_t p2 = ((size_t)adj_out[j + 2] << 10) + lo2;
        size_t p3 = ((size_t)adj_out[j + 3] << 10) + lo2;
        size_t p4 = ((size_t)adj_out[j + 4] << 10) + lo2;
        size_t p5 = ((size_t)adj_out[j + 5] << 10) + lo2;
        size_t p6 = ((size_t)adj_out[j + 6] << 10) + lo2;
        size_t p7 = ((size_t)adj_out[j + 7] << 10) + lo2;
        u32 h0 = *(const u16*)(ob + p0), u0 = *(const u16*)(ob + p0 + 128);
        u32 h1 = *(const u16*)(ob + p1), u1 = *(const u16*)(ob + p1 + 128);
        u32 h2 = *(const u16*)(ob + p2), u2 = *(const u16*)(ob + p2 + 128);
        u32 h3 = *(const u16*)(ob + p3), u3 = *(const u16*)(ob + p3 + 128);
        u32 h4 = *(const u16*)(ob + p4), u4 = *(const u16*)(ob + p4 + 128);
        u32 h5 = *(const u16*)(ob + p5), u5 = *(const u16*)(ob + p5 + 128);
        u32 h6 = *(const u16*)(ob + p6), u6 = *(const u16*)(ob + p6 + 128);
        u32 h7 = *(const u16*)(ob + p7), u7 = *(const u16*)(ob + p7 + 128);
        sH0 += (h0 & 255) + (h1 & 255) + (h2 & 255) + (h3 & 255) +
               (h4 & 255) + (h5 & 255) + (h6 & 255) + (h7 & 255);
        sH1 += (h0 >> 8) + (h1 >> 8) + (h2 >> 8) + (h3 >> 8) +
               (h4 >> 8) + (h5 >> 8) + (h6 >> 8) + (h7 >> 8);
        sU0 += (u0 & 255) + (u1 & 255) + (u2 & 255) + (u3 & 255) +
               (u4 & 255) + (u5 & 255) + (u6 & 255) + (u7 & 255);
        sU1 += (u0 >> 8) + (u1 >> 8) + (u2 >> 8) + (u3 >> 8) +
               (u4 >> 8) + (u5 >> 8) + (u6 >> 8) + (u7 >> 8);
    }
    for (; j < a1; j++) {
        size_t p = ((size_t)adj_out[j] << 10) + lo2;
        u32 h = *(const u16*)(ob + p), u = *(const u16*)(ob + p + 128);
        sH0 += h & 255; sH1 += h >> 8;
        sU0 += u & 255; sU1 += u >> 8;
    }
    j = b0;
    for (; j + 7 < b1; j += 8) {
        size_t p0 = ((size_t)adj_in[j] << 10) + lo2 + 128;
        size_t p1 = ((size_t)adj_in[j + 1] << 10) + lo2 + 128;
        size_t p2 = ((size_t)adj_in[j + 2] << 10) + lo2 + 128;
        size_t p3 = ((size_t)adj_in[j + 3] << 10) + lo2 + 128;
        size_t p4 = ((size_t)adj_in[j + 4] << 10) + lo2 + 128;
        size_t p5 = ((size_t)adj_in[j + 5] << 10) + lo2 + 128;
        size_t p6 = ((size_t)adj_in[j + 6] << 10) + lo2 + 128;
        size_t p7 = ((size_t)adj_in[j + 7] << 10) + lo2 + 128;
        u32 u0 = *(const u16*)(ob + p0), u1 = *(const u16*)(ob + p1);
        u32 u2 = *(const u16*)(ob + p2), u3 = *(const u16*)(ob + p3);
        u32 u4 = *(const u16*)(ob + p4), u5 = *(const u16*)(ob + p5);
        u32 u6 = *(const u16*)(ob + p6), u7 = *(const u16*)(ob + p7);
        sU0 += (u0 & 255) + (u1 & 255) + (u2 & 255) + (u3 & 255) +
               (u4 & 255) + (u5 & 255) + (u6 & 255) + (u7 & 255);
        sU1 += (u0 >> 8) + (u1 >> 8) + (u2 >> 8) + (u3 >> 8) +
               (u4 >> 8) + (u5 >> 8) + (u6 >> 8) + (u7 >> 8);
    }
    for (; j < b1; j++) {
        size_t p = ((size_t)adj_in[j] << 10) + lo2 + 128;
        u32 u = *(const u16*)(ob + p);
        sU0 += u & 255; sU1 += u >> 8;
    }
    const int degO = a1 - a0;
    const int degU = degO + (b1 - b0);
    const float invO = degO ? 1.f / (float)degO : 0.f;
    const float invU = degU ? 1.f / (float)degU : 0.f;
    float2 mh = *(const float2*)&maxH[lo2];
    float2 mu = *(const float2*)&maxU[lo2];
    const float c = 1.f / 255.f;
    u32 pH = f2bf((float)sH0 * mh.x * c * invO) |
             (f2bf((float)sH1 * mh.y * c * invO) << 16);
    u32 pU = f2bf((float)sU0 * mu.x * c * invU) |
             (f2bf((float)sU1 * mu.y * c * invU) << 16);
    u8* orow = (u8*)ob + ((size_t)node << 10);
    *(u32*)(orow + 512 + lane * 4) = pH;
    *(u32*)(orow + 768 + lane * 4) = pU;
}

// MFMA dual-GEMM tile: 16 rows x 128 cols per wave, A/B-frags in regs, B-frags
// of weights read from untransposed bf16 [128][K]. Layouts (gfx950 16x16x32
// bf16): A row=lane&15, k=8*(lane>>4)+j; C/D col=lane&15, row=(lane>>4)*4+reg.
// OUT_BF16=1: bf16 store + per-column max (LDS reduce -> global atomicMax on
// ints; valid: post-relu values >= 0). OUT_BF16=0: NT fp32 store (write-once).
template <int KC, int OUT_BF16>  // KC = K/32
__device__ __forceinline__ void gemm_tile(
        const u16* __restrict__ A, int lda,
        const u16* __restrict__ B, int ldb,
        const u16* __restrict__ W1, const u16* __restrict__ W2,
        const float* __restrict__ bias,
        float* __restrict__ OutF, int ldo, u16* __restrict__ OutB,
        int* __restrict__ colmax, int n, int blk) {
    constexpr int K = KC * 32;
    __shared__ int lmax[128];
    const int tid = threadIdx.x;
    const int lane = tid & 63;
    const int wave = tid >> 6;
    if (OUT_BF16) {
        if (tid < 128) lmax[tid] = 0;
        __syncthreads();
    }
    const int r0 = blk * 64 + wave * 16;
    const int arow = r0 + (lane & 15);
    const int crow = (arow < n) ? arow : n - 1;
    const int kof = (lane >> 4) * 8;

    bf16x8 a1[KC], a2[KC];
#pragma unroll
    for (int kc = 0; kc < KC; kc++) {
        a1[kc] = *(const bf16x8*)&A[(size_t)crow * lda + kc * 32 + kof];
        a2[kc] = *(const bf16x8*)&B[(size_t)crow * ldb + kc * 32 + kof];
    }
    const int wr = lane & 15;
    const int rbase = r0 + (lane >> 4) * 4;
#pragma unroll
    for (int c = 0; c < 8; c++) {
        f32x4 acc = {0.f, 0.f, 0.f, 0.f};
        const size_t wof = (size_t)(c * 16 + wr) * K + kof;
#pragma unroll
        for (int kc = 0; kc < KC; kc++) {
            acc = __builtin_amdgcn_mfma_f32_16x16x32_bf16(
                a1[kc], *(const bf16x8*)&W1[wof + kc * 32], acc, 0, 0, 0);
            acc = __builtin_amdgcn_mfma_f32_16x16x32_bf16(
                a2[kc], *(const bf16x8*)&W2[wof + kc * 32], acc, 0, 0, 0);
        }
        const int col = c * 16 + wr;
        const float bv = bias[col];
        float cmax = 0.f;
#pragma unroll
        for (int r = 0; r < 4; r++) {
            const int row = rbase + r;
            if (row < n) {
                float v = acc[r] + bv;
                if (OUT_BF16) {
                    v = fmaxf(v, 0.f);  // relu (L0 layers)
                    cmax = fmaxf(cmax, v);
                    OutB[(size_t)row * 128 + col] = (u16)f2bf(v);
                } else {
                    __builtin_nontemporal_store(v, &OutF[(size_t)row * ldo + col]);
                }
            }
        }
        if (OUT_BF16) atomicMax(&lmax[col], __float_as_int(cmax));
    }
    if (OUT_BF16) {
        __syncthreads();
        if (tid < 128) atomicMax(&colmax[tid], lmax[tid]);
    }
}

// fused L0 gemm: both heads in one dispatch (head = blockIdx.x >= nblk)
__global__ void __launch_bounds__(256) k_gemm_l0_fused(
        const u16* __restrict__ xb,
        const u16* __restrict__ agg0b, const u16* __restrict__ aggUb,
        const u16* __restrict__ Wsb0, const u16* __restrict__ Wnb0,
        const float* __restrict__ b0,
        u16* __restrict__ h1b, u16* __restrict__ u1b,
        int* __restrict__ maxH, int* __restrict__ maxU, int n, int nblk) {
    const int head = (blockIdx.x >= nblk) ? 1 : 0;
    const int blk = blockIdx.x - head * nblk;
    gemm_tile<2, 1>(xb, 64, head ? aggUb : agg0b, 64,
                    Wsb0 + head * 128 * 64, Wnb0 + head * 128 * 64,
                    b0 + head * 128, (float*)nullptr, 0,
                    head ? u1b : h1b, head ? maxU : maxH, n, blk);
}

// L1 gemm: A = h1b/u1b (ws bf16 [N][128]); B = agg rows in d_out strided
// (ldb=512 u16, pre-offset by caller). Separate dispatches per head (fusing
// would race: head1 writes the bytes holding head0's B rows).
__global__ void __launch_bounds__(256) k_gemm_l1(
        const u16* __restrict__ A, const u16* __restrict__ B,
        const u16* __restrict__ W1, const u16* __restrict__ W2,
        const float* __restrict__ bias, float* __restrict__ OutF, int ldo,
        int n) {
    gemm_tile<4, 0>(A, 128, B, 512, W1, W2, bias, OutF, ldo,
                    (u16*)nullptr, (int*)nullptr, n, blockIdx.x);
}

extern "C" void kernel_launch(void* const* d_in, const int* in_sizes, int n_in,
                              void* d_out, int out_size, void* d_ws, size_t ws_size,
                              hipStream_t stream) {
    const float* x = (const float*)d_in[0];
    const int* src = (const int*)d_in[1];
    const int* dst = (const int*)d_in[2];
    const float* Wn0 = (const float*)d_in[3];
    const float* Ws0 = (const float*)d_in[4];
    const float* b0 = (const float*)d_in[5];
    const float* Wn1 = (const float*)d_in[6];
    const float* Ws1 = (const float*)d_in[7];
    const float* b1 = (const float*)d_in[8];

    const int N = in_sizes[0] / 64;
    const int E = in_sizes[1];
    float* out = (float*)d_out;
    const int NB = (N + 255) >> 8;  // buckets of 256 nodes (must be <= 512)

    // ---- workspace layout (~91 MB, unchanged from R8) ----
    char* w = (char*)d_ws;
    size_t o = 0;
    auto alloc = [&](size_t bytes) -> void* {
        o = (o + 255) & ~(size_t)255;
        void* p = w + o;
        o += bytes;
        return p;
    };
    int* off_in = (int*)alloc((size_t)(N + 1) * 4);
    int* off_out = (int*)alloc((size_t)(N + 1) * 4);
    int* cntD = (int*)alloc(512 * 4);
    int* cntS = (int*)alloc(512 * 4);
    int* curD = (int*)alloc(512 * 4);
    int* curS = (int*)alloc(512 * 4);
    int* bbaseD = (int*)alloc(513 * 4);
    int* bbaseS = (int*)alloc(513 * 4);
    float* maxH = (float*)alloc(128 * 4);
    float* maxU = (float*)alloc(128 * 4);
    int* adj_in = (int*)alloc((size_t)E * 4);
    int* adj_out = (int*)alloc((size_t)E * 4);
    u16* AGGb = (u16*)alloc((size_t)N * 128 * 2);  // L0 agg: 2x[N][64]
    u16* h1b = (u16*)alloc((size_t)N * 128 * 2);
    u16* u1b = (u16*)alloc((size_t)N * 128 * 2);
    u16* Wsb0 = (u16*)alloc(2 * 128 * 64 * 2);
    u16* Wnb0 = (u16*)alloc(2 * 128 * 64 * 2);
    u16* Wsb1 = (u16*)alloc(2 * 128 * 128 * 2);
    u16* Wnb1 = (u16*)alloc(2 * 128 * 128 * 2);
    (void)ws_size;

    // pair arrays alias h1b/u1b (dead until the L0 gemm runs, after pass D)
    u32* pairsD = (u32*)h1b;
    u32* pairsS = (u32*)u1b;
    // d_out scratch, time-phased:
    //  phase A (prep..L0): xb bf16 @0 (12.8M), xq fp8 @16M (6.4M)
    //  phase B (quant..L1): per-row 1KB slots: h1q[0,128) u1q[128,256)
    //                       aggH[512,768) aggU[768,1024)
    u16* xb = (u16*)d_out;
    u8* xq = (u8*)d_out + (16 << 20);
    u8* ob = (u8*)d_out;

    const int n4 = N * 64 / 4;
    const int edgeBlocks = ((E + 7) / 8 + 255) / 256;

    // ---- fused prep ----
    k_prep<<<(n4 + 98304 + 255) / 256, 256, 0, stream>>>(
        x, xb, xq, n4, cntD, (int*)maxH, Ws0, Wn0, Ws1, Wn1, Wsb0, Wnb0, Wsb1, Wnb1);

    // ---- CSR build via bucketed counting sort ----
    k_bincnt<<<edgeBlocks, 256, 0, stream>>>(src, dst, cntD, cntS, E, NB);
    k_binscan<<<1, 512, 0, stream>>>(cntD, cntS, bbaseD, bbaseS, curD, curS,
                                     off_in, off_out, NB, N, E);
    k_binscatter<<<edgeBlocks, 256, 0, stream>>>(src, dst, curD, curS, pairsD, pairsS, E, NB);
    k_bucket_csr<<<2 * NB, 256, 0, stream>>>(pairsD, pairsS, bbaseD, bbaseS,
                                             off_in, adj_in, off_out, adj_out, N);

    const int nodeBlocks = (N + 3) / 4;
    const int gemmBlocks = (N + 63) / 64;

    // ---- layer 0 ----
    u16* agg0b = AGGb;                    // [N][64]
    u16* aggUb = AGGb + (size_t)N * 64;   // [N][64]
    k_agg_l0_q<<<nodeBlocks, 256, 0, stream>>>(xq, off_in, adj_in, off_out, adj_out,
                                               agg0b, aggUb, N);
    k_gemm_l0_fused<<<2 * gemmBlocks, 256, 0, stream>>>(
        xb, agg0b, aggUb, Wsb0, Wnb0, b0, h1b, u1b, (int*)maxH, (int*)maxU, N, gemmBlocks);

    // ---- quantize h1/u1 to per-feature uint8 into d_out slots ----
    k_quant<<<(2 * N * 16 + 255) / 256, 256, 0, stream>>>(h1b, u1b, maxH, maxU, ob, N);

    // ---- fused L1 aggregation (head0: h1 over out; head1: u1 over in+out) ----
    k_agg_l1_f<<<nodeBlocks, 256, 0, stream>>>(ob, off_in, adj_in, off_out, adj_out,
                                               maxH, maxU, N);

    // ---- L1 gemms (sequential; see race note on k_gemm_l1) ----
    k_gemm_l1<<<gemmBlocks, 256, 0, stream>>>(h1b, (const u16*)d_out + 256,
                                              Wsb1, Wnb1, b1, out, 256, N);
    k_gemm_l1<<<gemmBlocks, 256, 0, stream>>>(u1b, (const u16*)d_out + 384,
                                              Wsb1 + 128 * 128, Wnb1 + 128 * 128,
                                              b1 + 128, out + 128, 256, N);
}

// Round 10
// 540.918 us; speedup vs baseline: 1.2119x; 1.0736x over previous
//
#include <hip/hip_runtime.h>
#include <hip/hip_fp8.h>

// ---------------------------------------------------------------------------
// SAGEMultiSwitchModel: 2 heads x 2 SAGE layers on N=100k nodes, E=1.6M edges.
// head0 dirs "OI", head1 "UU". Layer: act([h|seg_mean(h)] @ [Ws|Wn]^T + b).
// R1: spill-free gemm. R2: bf16 gather tables. R4: bucketed-sort CSR build.
// R5: MFMA gemms. R6: fp8 x-table for L0 agg. R7: NT only on final store.
// R9: uint8 L1 gather tables + fused int-sum L1 agg (2x138us -> 142us).
// R10: agg_l1 was part-VALU-bound (53% busy, 1.93 of 2.55 TB/s plateau):
//      v_perm_b32 packed 16-bit-field accumulation (4->2.4 VALU/value, exact);
//      L1 gemms fused into one dispatch (aggH moved to ws AGGb; aggU stays in
//      d_out row bytes [768,1024) - head1 reads B into regs before stores).
// d_out row r (1024B): [0,128)=h1q [128,256)=u1q [768,1024)=aggU.
// ---------------------------------------------------------------------------

typedef unsigned short u16;
typedef unsigned int u32;
typedef unsigned char u8;
typedef __bf16 bf16x8 __attribute__((ext_vector_type(8)));
typedef float f32x4 __attribute__((ext_vector_type(4)));

__device__ __forceinline__ u32 f2bf(float f) {  // RNE float->bf16 (low 16 bits)
    u32 u = __float_as_uint(f);
    return (u + 0x7fffu + ((u >> 16) & 1u)) >> 16;
}
__device__ __forceinline__ float bf_lo(u32 v) { return __uint_as_float(v << 16); }
__device__ __forceinline__ float bf_hi(u32 v) { return __uint_as_float(v & 0xffff0000u); }
__device__ __forceinline__ u8 f2q(float f) {  // float -> fp8 e4m3 (OCP)
    __hip_fp8_e4m3 t(f);
    return *(u8*)&t;
}
__device__ __forceinline__ float q2f(u8 b) {
    __hip_fp8_e4m3 t;
    *(u8*)&t = b;
    return (float)t;
}
// spread byte pair (b0,b1) of v into 16-bit fields: b0 | (b1<<16). one v_perm.
__device__ __forceinline__ u32 sprd(u32 v) {
    return __builtin_amdgcn_perm(0u, v, 0x04010400u);
}

// fused prep: zero cnt[1024]+maxs[256]; x -> bf16 xb AND fp8 xq; weights bf16
__global__ void k_prep(const float* __restrict__ x, u16* __restrict__ xb,
                       u8* __restrict__ xq, int n4, int* __restrict__ cntzero,
                       int* __restrict__ maxzero,
                       const float* __restrict__ Ws0, const float* __restrict__ Wn0,
                       const float* __restrict__ Ws1, const float* __restrict__ Wn1,
                       u16* __restrict__ Wsb0, u16* __restrict__ Wnb0,
                       u16* __restrict__ Wsb1, u16* __restrict__ Wnb1) {
    int i = blockIdx.x * blockDim.x + threadIdx.x;
    if (i < 1024) cntzero[i] = 0;
    if (i < 256) maxzero[i] = 0;
    if (i < n4) {
        float4 v = *(const float4*)&x[(size_t)i * 4];
        u32 p0 = f2bf(v.x) | (f2bf(v.y) << 16);
        u32 p1 = f2bf(v.z) | (f2bf(v.w) << 16);
        *(uint2*)&xb[(size_t)i * 4] = make_uint2(p0, p1);
        u32 q = (u32)f2q(v.x) | ((u32)f2q(v.y) << 8) |
                ((u32)f2q(v.z) << 16) | ((u32)f2q(v.w) << 24);
        *(u32*)&xq[(size_t)i * 4] = q;
        return;
    }
    int t = i - n4;
    if (t < 16384) Wsb0[t] = (u16)f2bf(Ws0[t]);
    else if (t < 32768) Wnb0[t - 16384] = (u16)f2bf(Wn0[t - 16384]);
    else if (t < 65536) Wsb1[t - 32768] = (u16)f2bf(Ws1[t - 32768]);
    else if (t < 98304) Wnb1[t - 65536] = (u16)f2bf(Wn1[t - 65536]);
}

// ---- bucketed CSR build: NPB=256 nodes/bucket, bucket = node>>8 ----

__global__ void __launch_bounds__(256) k_bincnt(
        const int* __restrict__ src, const int* __restrict__ dst,
        int* cntD, int* cntS, int E, int NB) {
    __shared__ int hD[512], hS[512];
    const int tid = threadIdx.x;
    for (int i = tid; i < NB; i += 256) { hD[i] = 0; hS[i] = 0; }
    __syncthreads();
    const int base = (blockIdx.x * 256 + tid) * 8;
#pragma unroll
    for (int i = 0; i < 8; i++) {
        if (base + i < E) {
            atomicAdd(&hD[dst[base + i] >> 8], 1);
            atomicAdd(&hS[src[base + i] >> 8], 1);
        }
    }
    __syncthreads();
    for (int i = tid; i < NB; i += 256) {
        if (hD[i]) atomicAdd(&cntD[i], hD[i]);
        if (hS[i]) atomicAdd(&cntS[i], hS[i]);
    }
}

__global__ void __launch_bounds__(512) k_binscan(
        const int* __restrict__ cntD, const int* __restrict__ cntS,
        int* bbaseD, int* bbaseS, int* curD, int* curS,
        int* off_in, int* off_out, int NB, int N, int E) {
    __shared__ int ts[512];
    const int tid = threadIdx.x;
    int v = (tid < NB) ? cntD[tid] : 0;
    ts[tid] = v;
    __syncthreads();
    for (int ofs = 1; ofs < 512; ofs <<= 1) {
        int t = (tid >= ofs) ? ts[tid - ofs] : 0;
        __syncthreads();
        ts[tid] += t;
        __syncthreads();
    }
    int ex = ts[tid] - v;
    if (tid < NB) { bbaseD[tid] = ex; curD[tid] = ex; }
    if (tid == NB - 1) bbaseD[NB] = ex + v;
    __syncthreads();
    v = (tid < NB) ? cntS[tid] : 0;
    ts[tid] = v;
    __syncthreads();
    for (int ofs = 1; ofs < 512; ofs <<= 1) {
        int t = (tid >= ofs) ? ts[tid - ofs] : 0;
        __syncthreads();
        ts[tid] += t;
        __syncthreads();
    }
    ex = ts[tid] - v;
    if (tid < NB) { bbaseS[tid] = ex; curS[tid] = ex; }
    if (tid == NB - 1) bbaseS[NB] = ex + v;
    if (tid == 0) { off_in[N] = E; off_out[N] = E; }
}

__global__ void __launch_bounds__(256) k_binscatter(
        const int* __restrict__ src, const int* __restrict__ dst,
        int* curD, int* curS, u32* __restrict__ pairsD, u32* __restrict__ pairsS,
        int E, int NB) {
    __shared__ int hD[512], hS[512], bD[512], bS[512];
    const int tid = threadIdx.x;
    for (int i = tid; i < NB; i += 256) { hD[i] = 0; hS[i] = 0; }
    __syncthreads();
    const int base = (blockIdx.x * 256 + tid) * 8;
    int sv[8], dv[8], rD[8], rS[8];
#pragma unroll
    for (int i = 0; i < 8; i++) {
        if (base + i < E) {
            sv[i] = src[base + i];
            dv[i] = dst[base + i];
            rD[i] = atomicAdd(&hD[dv[i] >> 8], 1);
            rS[i] = atomicAdd(&hS[sv[i] >> 8], 1);
        }
    }
    __syncthreads();
    for (int i = tid; i < NB; i += 256) {
        bD[i] = hD[i] ? atomicAdd(&curD[i], hD[i]) : 0;
        bS[i] = hS[i] ? atomicAdd(&curS[i], hS[i]) : 0;
    }
    __syncthreads();
#pragma unroll
    for (int i = 0; i < 8; i++) {
        if (base + i < E) {
            pairsD[bD[dv[i] >> 8] + rD[i]] = ((u32)(dv[i] & 255) << 24) | (u32)sv[i];
            pairsS[bS[sv[i] >> 8] + rS[i]] = ((u32)(sv[i] & 255) << 24) | (u32)dv[i];
        }
    }
}

__global__ void __launch_bounds__(256) k_bucket_csr(
        const u32* __restrict__ pairsD, const u32* __restrict__ pairsS,
        const int* __restrict__ bbaseD, const int* __restrict__ bbaseS,
        int* __restrict__ off_in, int* __restrict__ adj_in,
        int* __restrict__ off_out, int* __restrict__ adj_out, int N) {
    __shared__ int cnt[256], cur[256], ts[256];
    const int b = blockIdx.x >> 1;
    const int arr = blockIdx.x & 1;
    const u32* pairs = arr ? pairsS : pairsD;
    const int* bbase = arr ? bbaseS : bbaseD;
    int* off = arr ? off_out : off_in;
    int* adj = arr ? adj_out : adj_in;
    const int e0 = bbase[b], e1 = bbase[b + 1];
    const int tid = threadIdx.x;
    cnt[tid] = 0;
    __syncthreads();
    for (int e = e0 + tid; e < e1; e += 256) atomicAdd(&cnt[pairs[e] >> 24], 1);
    __syncthreads();
    int v = cnt[tid];
    ts[tid] = v;
    __syncthreads();
    for (int ofs = 1; ofs < 256; ofs <<= 1) {
        int t = (tid >= ofs) ? ts[tid - ofs] : 0;
        __syncthreads();
        ts[tid] += t;
        __syncthreads();
    }
    const int ex = ts[tid] - v;
    const int n = b * 256 + tid;
    if (n < N) off[n] = e0 + ex;
    cur[tid] = e0 + ex;
    __syncthreads();
    for (int e = e0 + tid; e < e1; e += 256) {
        u32 p = pairs[e];
        int w = atomicAdd(&cur[p >> 24], 1);
        adj[w] = (int)(p & 0xFFFFFFu);
    }
}

// layer-0 aggregation: F=64 fp8 gather (1 byte/lane, 64B/row), x8 unrolled.
__global__ void __launch_bounds__(256) k_agg_l0_q(
        const u8* __restrict__ xq,
        const int* __restrict__ off_in, const int* __restrict__ adj_in,
        const int* __restrict__ off_out, const int* __restrict__ adj_out,
        u16* __restrict__ agg0b, u16* __restrict__ aggUb, int n) {
    const int node = blockIdx.x * 4 + (threadIdx.x >> 6);
    const int lane = threadIdx.x & 63;
    if (node >= n) return;
    const int a0 = off_in[node], a1 = off_in[node + 1];
    const int b0 = off_out[node], b1 = off_out[node + 1];
    float sin_ = 0.f, sout_ = 0.f;
    int j = a0;
    for (; j + 7 < a1; j += 8) {
        int i0 = adj_in[j], i1 = adj_in[j + 1], i2 = adj_in[j + 2], i3 = adj_in[j + 3];
        int i4 = adj_in[j + 4], i5 = adj_in[j + 5], i6 = adj_in[j + 6], i7 = adj_in[j + 7];
        float v0 = q2f(xq[(size_t)i0 * 64 + lane]);
        float v1 = q2f(xq[(size_t)i1 * 64 + lane]);
        float v2 = q2f(xq[(size_t)i2 * 64 + lane]);
        float v3 = q2f(xq[(size_t)i3 * 64 + lane]);
        float v4 = q2f(xq[(size_t)i4 * 64 + lane]);
        float v5 = q2f(xq[(size_t)i5 * 64 + lane]);
        float v6 = q2f(xq[(size_t)i6 * 64 + lane]);
        float v7 = q2f(xq[(size_t)i7 * 64 + lane]);
        sin_ += ((v0 + v1) + (v2 + v3)) + ((v4 + v5) + (v6 + v7));
    }
    for (; j < a1; j++) sin_ += q2f(xq[(size_t)adj_in[j] * 64 + lane]);
    j = b0;
    for (; j + 7 < b1; j += 8) {
        int i0 = adj_out[j], i1 = adj_out[j + 1], i2 = adj_out[j + 2], i3 = adj_out[j + 3];
        int i4 = adj_out[j + 4], i5 = adj_out[j + 5], i6 = adj_out[j + 6], i7 = adj_out[j + 7];
        float v0 = q2f(xq[(size_t)i0 * 64 + lane]);
        float v1 = q2f(xq[(size_t)i1 * 64 + lane]);
        float v2 = q2f(xq[(size_t)i2 * 64 + lane]);
        float v3 = q2f(xq[(size_t)i3 * 64 + lane]);
        float v4 = q2f(xq[(size_t)i4 * 64 + lane]);
        float v5 = q2f(xq[(size_t)i5 * 64 + lane]);
        float v6 = q2f(xq[(size_t)i6 * 64 + lane]);
        float v7 = q2f(xq[(size_t)i7 * 64 + lane]);
        sout_ += ((v0 + v1) + (v2 + v3)) + ((v4 + v5) + (v6 + v7));
    }
    for (; j < b1; j++) sout_ += q2f(xq[(size_t)adj_out[j] * 64 + lane]);
    const int din = a1 - a0, dout = b1 - b0;
    const int du = din + dout;
    agg0b[(size_t)node * 64 + lane] = (u16)f2bf(din ? sin_ / (float)din : 0.f);
    aggUb[(size_t)node * 64 + lane] = (u16)f2bf(du ? (sin_ + sout_) / (float)du : 0.f);
}

// quantize h1b/u1b (bf16 [N][128]) -> uint8 per-feature-scaled, into d_out
// strided slots: row r bytes [1024r + head*128, +128).
__global__ void __launch_bounds__(256) k_quant(
        const u16* __restrict__ h1b, const u16* __restrict__ u1b,
        const float* __restrict__ maxH, const float* __restrict__ maxU,
        u8* __restrict__ ob, int N) {
    int i = blockIdx.x * blockDim.x + threadIdx.x;  // 8 elems/thread
    const int total = N * 16;
    if (i >= 2 * total) return;
    const int head = (i >= total) ? 1 : 0;
    int t = i - head * total;
    const int row = t >> 4, seg = t & 15;
    const u16* src = head ? u1b : h1b;
    const float* mx = head ? maxU : maxH;
    uint4 v = *(const uint4*)&src[(size_t)row * 128 + seg * 8];
    float4 m0 = *(const float4*)&mx[seg * 8];
    float4 m1 = *(const float4*)&mx[seg * 8 + 4];
    float rs0 = m0.x > 0.f ? 255.f / m0.x : 0.f;
    float rs1 = m0.y > 0.f ? 255.f / m0.y : 0.f;
    float rs2 = m0.z > 0.f ? 255.f / m0.z : 0.f;
    float rs3 = m0.w > 0.f ? 255.f / m0.w : 0.f;
    float rs4 = m1.x > 0.f ? 255.f / m1.x : 0.f;
    float rs5 = m1.y > 0.f ? 255.f / m1.y : 0.f;
    float rs6 = m1.z > 0.f ? 255.f / m1.z : 0.f;
    float rs7 = m1.w > 0.f ? 255.f / m1.w : 0.f;
    u32 q0 = (u32)fminf(rintf(bf_lo(v.x) * rs0), 255.f);
    u32 q1 = (u32)fminf(rintf(bf_hi(v.x) * rs1), 255.f);
    u32 q2 = (u32)fminf(rintf(bf_lo(v.y) * rs2), 255.f);
    u32 q3 = (u32)fminf(rintf(bf_hi(v.y) * rs3), 255.f);
    u32 q4 = (u32)fminf(rintf(bf_lo(v.z) * rs4), 255.f);
    u32 q5 = (u32)fminf(rintf(bf_hi(v.z) * rs5), 255.f);
    u32 q6 = (u32)fminf(rintf(bf_lo(v.w) * rs6), 255.f);
    u32 q7 = (u32)fminf(rintf(bf_hi(v.w) * rs7), 255.f);
    uint2 p;
    p.x = q0 | (q1 << 8) | (q2 << 16) | (q3 << 24);
    p.y = q4 | (q5 << 8) | (q6 << 16) | (q7 << 24);
    *(uint2*)(ob + ((size_t)row << 10) + head * 128 + seg * 8) = p;
}

// fused L1 aggregation: per node, out-adj gathers h1q AND u1q (shared idx),
// in-adj gathers u1q. v_perm packed 16-bit-field integer sums (exact; fields
// flushed every 8 values, max 2040 per field). aggH -> ws (bf16 [N][128]);
// aggU -> d_out row bytes [768,1024).
__global__ void __launch_bounds__(256) k_agg_l1_f(
        const u8* __restrict__ ob,
        const int* __restrict__ off_in, const int* __restrict__ adj_in,
        const int* __restrict__ off_out, const int* __restrict__ adj_out,
        const float* __restrict__ maxH, const float* __restrict__ maxU,
        u16* __restrict__ aggH, int n) {
    const int node = blockIdx.x * 4 + (threadIdx.x >> 6);
    const int lane = threadIdx.x & 63;
    if (node >= n) return;
    const int a0 = off_out[node], a1 = off_out[node + 1];  // out-adj: h1 + u1
    const int b0 = off_in[node], b1 = off_in[node + 1];    // in-adj: u1 only
    u32 sH0 = 0, sH1 = 0, sU0 = 0, sU1 = 0;
    const int lo2 = lane * 2;
    int j = a0;
    for (; j + 7 < a1; j += 8) {
        size_t p0 = ((size_t)adj_out[j] << 10) + lo2;
        size_t p1 = ((size_t)adj_out[j + 1] << 10) + lo2;
        size_t p2 = ((size_t)adj_out[j + 2] << 10) + lo2;
        size_t p3 = ((size_t)adj_out[j + 3] << 10) + lo2;
        size_t p4 = ((size_t)adj_out[j + 4] << 10) + lo2;
        size_t p5 = ((size_t)adj_out[j + 5] << 10) + lo2;
        size_t p6 = ((size_t)adj_out[j + 6] << 10) + lo2;
        size_t p7 = ((size_t)adj_out[j + 7] << 10) + lo2;
        u32 h0 = *(const u16*)(ob + p0), u0 = *(const u16*)(ob + p0 + 128);
        u32 h1 = *(const u16*)(ob + p1), u1 = *(const u16*)(ob + p1 + 128);
        u32 h2 = *(const u16*)(ob + p2), u2 = *(const u16*)(ob + p2 + 128);
        u32 h3 = *(const u16*)(ob + p3), u3 = *(const u16*)(ob + p3 + 128);
        u32 h4 = *(const u16*)(ob + p4), u4 = *(const u16*)(ob + p4 + 128);
        u32 h5 = *(const u16*)(ob + p5), u5 = *(const u16*)(ob + p5 + 128);
        u32 h6 = *(const u16*)(ob + p6), u6 = *(const u16*)(ob + p6 + 128);
        u32 h7 = *(const u16*)(ob + p7), u7 = *(const u16*)(ob + p7 + 128);
        u32 aH = ((sprd(h0) + sprd(h1)) + (sprd(h2) + sprd(h3))) +
                 ((sprd(h4) + sprd(h5)) + (sprd(h6) + sprd(h7)));
        u32 aU = ((sprd(u0) + sprd(u1)) + (sprd(u2) + sprd(u3))) +
                 ((sprd(u4) + sprd(u5)) + (sprd(u6) + sprd(u7)));
        sH0 += aH & 0xFFFFu; sH1 += aH >> 16;
        sU0 += aU & 0xFFFFu; sU1 += aU >> 16;
    }
    for (; j < a1; j++) {
        size_t p = ((size_t)adj_out[j] << 10) + lo2;
        u32 h = *(const u16*)(ob + p), u = *(const u16*)(ob + p + 128);
        sH0 += h & 255; sH1 += h >> 8;
        sU0 += u & 255; sU1 += u >> 8;
    }
    j = b0;
    for (; j + 7 < b1; j += 8) {
        size_t p0 = ((size_t)adj_in[j] << 10) + lo2 + 128;
        size_t p1 = ((size_t)adj_in[j + 1] << 10) + lo2 + 128;
        size_t p2 = ((size_t)adj_in[j + 2] << 10) + lo2 + 128;
        size_t p3 = ((size_t)adj_in[j + 3] << 10) + lo2 + 128;
        size_t p4 = ((size_t)adj_in[j + 4] << 10) + lo2 + 128;
        size_t p5 = ((size_t)adj_in[j + 5] << 10) + lo2 + 128;
        size_t p6 = ((size_t)adj_in[j + 6] << 10) + lo2 + 128;
        size_t p7 = ((size_t)adj_in[j + 7] << 10) + lo2 + 128;
        u32 u0 = *(const u16*)(ob + p0), u1 = *(const u16*)(ob + p1);
        u32 u2 = *(const u16*)(ob + p2), u3 = *(const u16*)(ob + p3);
        u32 u4 = *(const u16*)(ob + p4), u5 = *(const u16*)(ob + p5);
        u32 u6 = *(const u16*)(ob + p6), u7 = *(const u16*)(ob + p7);
        u32 aU = ((sprd(u0) + sprd(u1)) + (sprd(u2) + sprd(u3))) +
                 ((sprd(u4) + sprd(u5)) + (sprd(u6) + sprd(u7)));
        sU0 += aU & 0xFFFFu; sU1 += aU >> 16;
    }
    for (; j < b1; j++) {
        size_t p = ((size_t)adj_in[j] << 10) + lo2 + 128;
        u32 u = *(const u16*)(ob + p);
        sU0 += u & 255; sU1 += u >> 8;
    }
    const int degO = a1 - a0;
    const int degU = degO + (b1 - b0);
    const float invO = degO ? 1.f / (float)degO : 0.f;
    const float invU = degU ? 1.f / (float)degU : 0.f;
    float2 mh = *(const float2*)&maxH[lo2];
    float2 mu = *(const float2*)&maxU[lo2];
    const float c = 1.f / 255.f;
    u32 pH = f2bf((float)sH0 * mh.x * c * invO) |
             (f2bf((float)sH1 * mh.y * c * invO) << 16);
    u32 pU = f2bf((float)sU0 * mu.x * c * invU) |
             (f2bf((float)sU1 * mu.y * c * invU) << 16);
    *(u32*)&aggH[(size_t)node * 128 + lo2] = pH;
    *(u32*)((u8*)ob + ((size_t)node << 10) + 768 + lane * 4) = pU;
}

// MFMA dual-GEMM tile: 16 rows x 128 cols per wave, A/B-frags in regs, B-frags
// of weights read from untransposed bf16 [128][K]. Layouts (gfx950 16x16x32
// bf16): A row=lane&15, k=8*(lane>>4)+j; C/D col=lane&15, row=(lane>>4)*4+reg.
// OUT_BF16=1: bf16 store + per-column max (LDS reduce -> global atomicMax on
// ints; valid: post-relu values >= 0). OUT_BF16=0: NT fp32 store (write-once).
template <int KC, int OUT_BF16>  // KC = K/32
__device__ __forceinline__ void gemm_tile(
        const u16* __restrict__ A, int lda,
        const u16* __restrict__ B, int ldb,
        const u16* __restrict__ W1, const u16* __restrict__ W2,
        const float* __restrict__ bias,
        float* __restrict__ OutF, int ldo, u16* __restrict__ OutB,
        int* __restrict__ colmax, int n, int blk) {
    constexpr int K = KC * 32;
    __shared__ int lmax[128];
    const int tid = threadIdx.x;
    const int lane = tid & 63;
    const int wave = tid >> 6;
    if (OUT_BF16) {
        if (tid < 128) lmax[tid] = 0;
        __syncthreads();
    }
    const int r0 = blk * 64 + wave * 16;
    const int arow = r0 + (lane & 15);
    const int crow = (arow < n) ? arow : n - 1;
    const int kof = (lane >> 4) * 8;

    bf16x8 a1[KC], a2[KC];
#pragma unroll
    for (int kc = 0; kc < KC; kc++) {
        a1[kc] = *(const bf16x8*)&A[(size_t)crow * lda + kc * 32 + kof];
        a2[kc] = *(const bf16x8*)&B[(size_t)crow * ldb + kc * 32 + kof];
    }
    const int wr = lane & 15;
    const int rbase = r0 + (lane >> 4) * 4;
#pragma unroll
    for (int c = 0; c < 8; c++) {
        f32x4 acc = {0.f, 0.f, 0.f, 0.f};
        const size_t wof = (size_t)(c * 16 + wr) * K + kof;
#pragma unroll
        for (int kc = 0; kc < KC; kc++) {
            acc = __builtin_amdgcn_mfma_f32_16x16x32_bf16(
                a1[kc], *(const bf16x8*)&W1[wof + kc * 32], acc, 0, 0, 0);
            acc = __builtin_amdgcn_mfma_f32_16x16x32_bf16(
                a2[kc], *(const bf16x8*)&W2[wof + kc * 32], acc, 0, 0, 0);
        }
        const int col = c * 16 + wr;
        const float bv = bias[col];
        float cmax = 0.f;
#pragma unroll
        for (int r = 0; r < 4; r++) {
            const int row = rbase + r;
            if (row < n) {
                float v = acc[r] + bv;
                if (OUT_BF16) {
                    v = fmaxf(v, 0.f);  // relu (L0 layers)
                    cmax = fmaxf(cmax, v);
                    OutB[(size_t)row * 128 + col] = (u16)f2bf(v);
                } else {
                    __builtin_nontemporal_store(v, &OutF[(size_t)row * ldo + col]);
                }
            }
        }
        if (OUT_BF16) atomicMax(&lmax[col], __float_as_int(cmax));
    }
    if (OUT_BF16) {
        __syncthreads();
        if (tid < 128) atomicMax(&colmax[tid], lmax[tid]);
    }
}

// fused L0 gemm: both heads in one dispatch (head = blockIdx.x >= nblk)
__global__ void __launch_bounds__(256) k_gemm_l0_fused(
        const u16* __restrict__ xb,
        const u16* __restrict__ agg0b, const u16* __restrict__ aggUb,
        const u16* __restrict__ Wsb0, const u16* __restrict__ Wnb0,
        const float* __restrict__ b0,
        u16* __restrict__ h1b, u16* __restrict__ u1b,
        int* __restrict__ maxH, int* __restrict__ maxU, int n, int nblk) {
    const int head = (blockIdx.x >= nblk) ? 1 : 0;
    const int blk = blockIdx.x - head * nblk;
    gemm_tile<2, 1>(xb, 64, head ? aggUb : agg0b, 64,
                    Wsb0 + head * 128 * 64, Wnb0 + head * 128 * 64,
                    b0 + head * 128, (float*)nullptr, 0,
                    head ? u1b : h1b, head ? maxU : maxH, n, blk);
}

// fused L1 gemm: head0 A=h1b B=aggH(ws, ldb=128); head1 A=u1b B=aggU in d_out
// rows at u16 offset 384, ldb=512. Safe in one dispatch: head0 writes out
// bytes [0,512) (disjoint from aggU at [768,1024)); head1 reads its B rows
// into registers before storing bytes [512,1024) (per-wave row-disjoint).
__global__ void __launch_bounds__(256) k_gemm_l1_fused(
        const u16* __restrict__ h1b, const u16* __restrict__ u1b,
        const u16* __restrict__ aggH, const u16* __restrict__ aggU,
        const u16* __restrict__ Wsb1, const u16* __restrict__ Wnb1,
        const float* __restrict__ b1,
        float* __restrict__ out, int n, int nblk) {
    const int head = (blockIdx.x >= nblk) ? 1 : 0;
    const int blk = blockIdx.x - head * nblk;
    if (head == 0) {
        gemm_tile<4, 0>(h1b, 128, aggH, 128, Wsb1, Wnb1, b1,
                        out, 256, (u16*)nullptr, (int*)nullptr, n, blk);
    } else {
        gemm_tile<4, 0>(u1b, 128, aggU, 512, Wsb1 + 128 * 128, Wnb1 + 128 * 128,
                        b1 + 128, out + 128, 256, (u16*)nullptr, (int*)nullptr, n, blk);
    }
}

extern "C" void kernel_launch(void* const* d_in, const int* in_sizes, int n_in,
                              void* d_out, int out_size, void* d_ws, size_t ws_size,
                              hipStream_t stream) {
    const float* x = (const float*)d_in[0];
    const int* src = (const int*)d_in[1];
    const int* dst = (const int*)d_in[2];
    const float* Wn0 = (const float*)d_in[3];
    const float* Ws0 = (const float*)d_in[4];
    const float* b0 = (const float*)d_in[5];
    const float* Wn1 = (const float*)d_in[6];
    const float* Ws1 = (const float*)d_in[7];
    const float* b1 = (const float*)d_in[8];

    const int N = in_sizes[0] / 64;
    const int E = in_sizes[1];
    float* out = (float*)d_out;
    const int NB = (N + 255) >> 8;  // buckets of 256 nodes (must be <= 512)

    // ---- workspace layout (~91 MB) ----
    char* w = (char*)d_ws;
    size_t o = 0;
    auto alloc = [&](size_t bytes) -> void* {
        o = (o + 255) & ~(size_t)255;
        void* p = w + o;
        o += bytes;
        return p;
    };
    int* off_in = (int*)alloc((size_t)(N + 1) * 4);
    int* off_out = (int*)alloc((size_t)(N + 1) * 4);
    int* cntD = (int*)alloc(512 * 4);
    int* cntS = (int*)alloc(512 * 4);
    int* curD = (int*)alloc(512 * 4);
    int* curS = (int*)alloc(512 * 4);
    int* bbaseD = (int*)alloc(513 * 4);
    int* bbaseS = (int*)alloc(513 * 4);
    float* maxH = (float*)alloc(128 * 4);
    float* maxU = (float*)alloc(128 * 4);
    int* adj_in = (int*)alloc((size_t)E * 4);
    int* adj_out = (int*)alloc((size_t)E * 4);
    u16* AGGb = (u16*)alloc((size_t)N * 128 * 2);  // L0 agg 2x[N][64]; L1 aggH
    u16* h1b = (u16*)alloc((size_t)N * 128 * 2);
    u16* u1b = (u16*)alloc((size_t)N * 128 * 2);
    u16* Wsb0 = (u16*)alloc(2 * 128 * 64 * 2);
    u16* Wnb0 = (u16*)alloc(2 * 128 * 64 * 2);
    u16* Wsb1 = (u16*)alloc(2 * 128 * 128 * 2);
    u16* Wnb1 = (u16*)alloc(2 * 128 * 128 * 2);
    (void)ws_size;

    // pair arrays alias h1b/u1b (dead until the L0 gemm runs, after pass D)
    u32* pairsD = (u32*)h1b;
    u32* pairsS = (u32*)u1b;
    // d_out scratch, time-phased:
    //  phase A (prep..L0): xb bf16 @0 (12.8M), xq fp8 @16M (6.4M)
    //  phase B (quant..L1): per-row 1KB slots: h1q[0,128) u1q[128,256)
    //                       aggU[768,1024)
    u16* xb = (u16*)d_out;
    u8* xq = (u8*)d_out + (16 << 20);
    u8* ob = (u8*)d_out;

    const int n4 = N * 64 / 4;
    const int edgeBlocks = ((E + 7) / 8 + 255) / 256;

    // ---- fused prep ----
    k_prep<<<(n4 + 98304 + 255) / 256, 256, 0, stream>>>(
        x, xb, xq, n4, cntD, (int*)maxH, Ws0, Wn0, Ws1, Wn1, Wsb0, Wnb0, Wsb1, Wnb1);

    // ---- CSR build via bucketed counting sort ----
    k_bincnt<<<edgeBlocks, 256, 0, stream>>>(src, dst, cntD, cntS, E, NB);
    k_binscan<<<1, 512, 0, stream>>>(cntD, cntS, bbaseD, bbaseS, curD, curS,
                                     off_in, off_out, NB, N, E);
    k_binscatter<<<edgeBlocks, 256, 0, stream>>>(src, dst, curD, curS, pairsD, pairsS, E, NB);
    k_bucket_csr<<<2 * NB, 256, 0, stream>>>(pairsD, pairsS, bbaseD, bbaseS,
                                             off_in, adj_in, off_out, adj_out, N);

    const int nodeBlocks = (N + 3) / 4;
    const int gemmBlocks = (N + 63) / 64;

    // ---- layer 0 ----
    u16* agg0b = AGGb;                    // [N][64]
    u16* aggUb = AGGb + (size_t)N * 64;   // [N][64]
    k_agg_l0_q<<<nodeBlocks, 256, 0, stream>>>(xq, off_in, adj_in, off_out, adj_out,
                                               agg0b, aggUb, N);
    k_gemm_l0_fused<<<2 * gemmBlocks, 256, 0, stream>>>(
        xb, agg0b, aggUb, Wsb0, Wnb0, b0, h1b, u1b, (int*)maxH, (int*)maxU, N, gemmBlocks);

    // ---- quantize h1/u1 to per-feature uint8 into d_out slots ----
    k_quant<<<(2 * N * 16 + 255) / 256, 256, 0, stream>>>(h1b, u1b, maxH, maxU, ob, N);

    // ---- fused L1 aggregation (aggH -> AGGb ws; aggU -> d_out rows) ----
    k_agg_l1_f<<<nodeBlocks, 256, 0, stream>>>(ob, off_in, adj_in, off_out, adj_out,
                                               maxH, maxU, AGGb, N);

    // ---- fused L1 gemm (both heads, one dispatch) ----
    k_gemm_l1_fused<<<2 * gemmBlocks, 256, 0, stream>>>(
        h1b, u1b, AGGb, (const u16*)d_out + 384, Wsb1, Wnb1, b1, out, N, gemmBlocks);
}

// Round 11
// 434.941 us; speedup vs baseline: 1.5072x; 1.2437x over previous
//
#include <hip/hip_runtime.h>
#include <hip/hip_fp8.h>

// ---------------------------------------------------------------------------
// SAGEMultiSwitchModel: 2 heads x 2 SAGE layers on N=100k nodes, E=1.6M edges.
// head0 dirs "OI", head1 "UU". Layer: act([h|seg_mean(h)] @ [Ws|Wn]^T + b).
// R1: spill-free gemm. R2: bf16 gather tables. R4: bucketed-sort CSR build.
// R5: MFMA gemms. R6: fp8 x-table for L0 agg. R7: NT only on final store.
// R9: uint8 L1 gather tables + fused int-sum L1 agg. R10: v_perm packed sums.
// R11: gemms were latency/L2-bound (MfmaUtil 4%!): each wave re-read all of
//      W1+W2 from global per 16-row tile (~800 MB L2 for L1). Now W staged in
//      LDS per 512-thread block (8 waves share; 128 rows/block), XOR-swizzled
//      (byte ^= (row&7)<<4) on write+read to kill stride-256B bank conflicts.
// d_out row r (1024B): [0,128)=h1q [128,256)=u1q [768,1024)=aggU.
// ---------------------------------------------------------------------------

typedef unsigned short u16;
typedef unsigned int u32;
typedef unsigned char u8;
typedef __bf16 bf16x8 __attribute__((ext_vector_type(8)));
typedef float f32x4 __attribute__((ext_vector_type(4)));

__device__ __forceinline__ u32 f2bf(float f) {  // RNE float->bf16 (low 16 bits)
    u32 u = __float_as_uint(f);
    return (u + 0x7fffu + ((u >> 16) & 1u)) >> 16;
}
__device__ __forceinline__ float bf_lo(u32 v) { return __uint_as_float(v << 16); }
__device__ __forceinline__ float bf_hi(u32 v) { return __uint_as_float(v & 0xffff0000u); }
__device__ __forceinline__ u8 f2q(float f) {  // float -> fp8 e4m3 (OCP)
    __hip_fp8_e4m3 t(f);
    return *(u8*)&t;
}
__device__ __forceinline__ float q2f(u8 b) {
    __hip_fp8_e4m3 t;
    *(u8*)&t = b;
    return (float)t;
}
// spread byte pair (b0,b1) of v into 16-bit fields: b0 | (b1<<16). one v_perm.
__device__ __forceinline__ u32 sprd(u32 v) {
    return __builtin_amdgcn_perm(0u, v, 0x04010400u);
}

// fused prep: zero cnt[1024]+maxs[256]; x -> bf16 xb AND fp8 xq; weights bf16
__global__ void k_prep(const float* __restrict__ x, u16* __restrict__ xb,
                       u8* __restrict__ xq, int n4, int* __restrict__ cntzero,
                       int* __restrict__ maxzero,
                       const float* __restrict__ Ws0, const float* __restrict__ Wn0,
                       const float* __restrict__ Ws1, const float* __restrict__ Wn1,
                       u16* __restrict__ Wsb0, u16* __restrict__ Wnb0,
                       u16* __restrict__ Wsb1, u16* __restrict__ Wnb1) {
    int i = blockIdx.x * blockDim.x + threadIdx.x;
    if (i < 1024) cntzero[i] = 0;
    if (i < 256) maxzero[i] = 0;
    if (i < n4) {
        float4 v = *(const float4*)&x[(size_t)i * 4];
        u32 p0 = f2bf(v.x) | (f2bf(v.y) << 16);
        u32 p1 = f2bf(v.z) | (f2bf(v.w) << 16);
        *(uint2*)&xb[(size_t)i * 4] = make_uint2(p0, p1);
        u32 q = (u32)f2q(v.x) | ((u32)f2q(v.y) << 8) |
                ((u32)f2q(v.z) << 16) | ((u32)f2q(v.w) << 24);
        *(u32*)&xq[(size_t)i * 4] = q;
        return;
    }
    int t = i - n4;
    if (t < 16384) Wsb0[t] = (u16)f2bf(Ws0[t]);
    else if (t < 32768) Wnb0[t - 16384] = (u16)f2bf(Wn0[t - 16384]);
    else if (t < 65536) Wsb1[t - 32768] = (u16)f2bf(Ws1[t - 32768]);
    else if (t < 98304) Wnb1[t - 65536] = (u16)f2bf(Wn1[t - 65536]);
}

// ---- bucketed CSR build: NPB=256 nodes/bucket, bucket = node>>8 ----

__global__ void __launch_bounds__(256) k_bincnt(
        const int* __restrict__ src, const int* __restrict__ dst,
        int* cntD, int* cntS, int E, int NB) {
    __shared__ int hD[512], hS[512];
    const int tid = threadIdx.x;
    for (int i = tid; i < NB; i += 256) { hD[i] = 0; hS[i] = 0; }
    __syncthreads();
    const int base = (blockIdx.x * 256 + tid) * 8;
#pragma unroll
    for (int i = 0; i < 8; i++) {
        if (base + i < E) {
            atomicAdd(&hD[dst[base + i] >> 8], 1);
            atomicAdd(&hS[src[base + i] >> 8], 1);
        }
    }
    __syncthreads();
    for (int i = tid; i < NB; i += 256) {
        if (hD[i]) atomicAdd(&cntD[i], hD[i]);
        if (hS[i]) atomicAdd(&cntS[i], hS[i]);
    }
}

__global__ void __launch_bounds__(512) k_binscan(
        const int* __restrict__ cntD, const int* __restrict__ cntS,
        int* bbaseD, int* bbaseS, int* curD, int* curS,
        int* off_in, int* off_out, int NB, int N, int E) {
    __shared__ int ts[512];
    const int tid = threadIdx.x;
    int v = (tid < NB) ? cntD[tid] : 0;
    ts[tid] = v;
    __syncthreads();
    for (int ofs = 1; ofs < 512; ofs <<= 1) {
        int t = (tid >= ofs) ? ts[tid - ofs] : 0;
        __syncthreads();
        ts[tid] += t;
        __syncthreads();
    }
    int ex = ts[tid] - v;
    if (tid < NB) { bbaseD[tid] = ex; curD[tid] = ex; }
    if (tid == NB - 1) bbaseD[NB] = ex + v;
    __syncthreads();
    v = (tid < NB) ? cntS[tid] : 0;
    ts[tid] = v;
    __syncthreads();
    for (int ofs = 1; ofs < 512; ofs <<= 1) {
        int t = (tid >= ofs) ? ts[tid - ofs] : 0;
        __syncthreads();
        ts[tid] += t;
        __syncthreads();
    }
    ex = ts[tid] - v;
    if (tid < NB) { bbaseS[tid] = ex; curS[tid] = ex; }
    if (tid == NB - 1) bbaseS[NB] = ex + v;
    if (tid == 0) { off_in[N] = E; off_out[N] = E; }
}

__global__ void __launch_bounds__(256) k_binscatter(
        const int* __restrict__ src, const int* __restrict__ dst,
        int* curD, int* curS, u32* __restrict__ pairsD, u32* __restrict__ pairsS,
        int E, int NB) {
    __shared__ int hD[512], hS[512], bD[512], bS[512];
    const int tid = threadIdx.x;
    for (int i = tid; i < NB; i += 256) { hD[i] = 0; hS[i] = 0; }
    __syncthreads();
    const int base = (blockIdx.x * 256 + tid) * 8;
    int sv[8], dv[8], rD[8], rS[8];
#pragma unroll
    for (int i = 0; i < 8; i++) {
        if (base + i < E) {
            sv[i] = src[base + i];
            dv[i] = dst[base + i];
            rD[i] = atomicAdd(&hD[dv[i] >> 8], 1);
            rS[i] = atomicAdd(&hS[sv[i] >> 8], 1);
        }
    }
    __syncthreads();
    for (int i = tid; i < NB; i += 256) {
        bD[i] = hD[i] ? atomicAdd(&curD[i], hD[i]) : 0;
        bS[i] = hS[i] ? atomicAdd(&curS[i], hS[i]) : 0;
    }
    __syncthreads();
#pragma unroll
    for (int i = 0; i < 8; i++) {
        if (base + i < E) {
            pairsD[bD[dv[i] >> 8] + rD[i]] = ((u32)(dv[i] & 255) << 24) | (u32)sv[i];
            pairsS[bS[sv[i] >> 8] + rS[i]] = ((u32)(sv[i] & 255) << 24) | (u32)dv[i];
        }
    }
}

__global__ void __launch_bounds__(256) k_bucket_csr(
        const u32* __restrict__ pairsD, const u32* __restrict__ pairsS,
        const int* __restrict__ bbaseD, const int* __restrict__ bbaseS,
        int* __restrict__ off_in, int* __restrict__ adj_in,
        int* __restrict__ off_out, int* __restrict__ adj_out, int N) {
    __shared__ int cnt[256], cur[256], ts[256];
    const int b = blockIdx.x >> 1;
    const int arr = blockIdx.x & 1;
    const u32* pairs = arr ? pairsS : pairsD;
    const int* bbase = arr ? bbaseS : bbaseD;
    int* off = arr ? off_out : off_in;
    int* adj = arr ? adj_out : adj_in;
    const int e0 = bbase[b], e1 = bbase[b + 1];
    const int tid = threadIdx.x;
    cnt[tid] = 0;
    __syncthreads();
    for (int e = e0 + tid; e < e1; e += 256) atomicAdd(&cnt[pairs[e] >> 24], 1);
    __syncthreads();
    int v = cnt[tid];
    ts[tid] = v;
    __syncthreads();
    for (int ofs = 1; ofs < 256; ofs <<= 1) {
        int t = (tid >= ofs) ? ts[tid - ofs] : 0;
        __syncthreads();
        ts[tid] += t;
        __syncthreads();
    }
    const int ex = ts[tid] - v;
    const int n = b * 256 + tid;
    if (n < N) off[n] = e0 + ex;
    cur[tid] = e0 + ex;
    __syncthreads();
    for (int e = e0 + tid; e < e1; e += 256) {
        u32 p = pairs[e];
        int w = atomicAdd(&cur[p >> 24], 1);
        adj[w] = (int)(p & 0xFFFFFFu);
    }
}

// layer-0 aggregation: F=64 fp8 gather (1 byte/lane, 64B/row), x8 unrolled.
__global__ void __launch_bounds__(256) k_agg_l0_q(
        const u8* __restrict__ xq,
        const int* __restrict__ off_in, const int* __restrict__ adj_in,
        const int* __restrict__ off_out, const int* __restrict__ adj_out,
        u16* __restrict__ agg0b, u16* __restrict__ aggUb, int n) {
    const int node = blockIdx.x * 4 + (threadIdx.x >> 6);
    const int lane = threadIdx.x & 63;
    if (node >= n) return;
    const int a0 = off_in[node], a1 = off_in[node + 1];
    const int b0 = off_out[node], b1 = off_out[node + 1];
    float sin_ = 0.f, sout_ = 0.f;
    int j = a0;
    for (; j + 7 < a1; j += 8) {
        int i0 = adj_in[j], i1 = adj_in[j + 1], i2 = adj_in[j + 2], i3 = adj_in[j + 3];
        int i4 = adj_in[j + 4], i5 = adj_in[j + 5], i6 = adj_in[j + 6], i7 = adj_in[j + 7];
        float v0 = q2f(xq[(size_t)i0 * 64 + lane]);
        float v1 = q2f(xq[(size_t)i1 * 64 + lane]);
        float v2 = q2f(xq[(size_t)i2 * 64 + lane]);
        float v3 = q2f(xq[(size_t)i3 * 64 + lane]);
        float v4 = q2f(xq[(size_t)i4 * 64 + lane]);
        float v5 = q2f(xq[(size_t)i5 * 64 + lane]);
        float v6 = q2f(xq[(size_t)i6 * 64 + lane]);
        float v7 = q2f(xq[(size_t)i7 * 64 + lane]);
        sin_ += ((v0 + v1) + (v2 + v3)) + ((v4 + v5) + (v6 + v7));
    }
    for (; j < a1; j++) sin_ += q2f(xq[(size_t)adj_in[j] * 64 + lane]);
    j = b0;
    for (; j + 7 < b1; j += 8) {
        int i0 = adj_out[j], i1 = adj_out[j + 1], i2 = adj_out[j + 2], i3 = adj_out[j + 3];
        int i4 = adj_out[j + 4], i5 = adj_out[j + 5], i6 = adj_out[j + 6], i7 = adj_out[j + 7];
        float v0 = q2f(xq[(size_t)i0 * 64 + lane]);
        float v1 = q2f(xq[(size_t)i1 * 64 + lane]);
        float v2 = q2f(xq[(size_t)i2 * 64 + lane]);
        float v3 = q2f(xq[(size_t)i3 * 64 + lane]);
        float v4 = q2f(xq[(size_t)i4 * 64 + lane]);
        float v5 = q2f(xq[(size_t)i5 * 64 + lane]);
        float v6 = q2f(xq[(size_t)i6 * 64 + lane]);
        float v7 = q2f(xq[(size_t)i7 * 64 + lane]);
        sout_ += ((v0 + v1) + (v2 + v3)) + ((v4 + v5) + (v6 + v7));
    }
    for (; j < b1; j++) sout_ += q2f(xq[(size_t)adj_out[j] * 64 + lane]);
    const int din = a1 - a0, dout = b1 - b0;
    const int du = din + dout;
    agg0b[(size_t)node * 64 + lane] = (u16)f2bf(din ? sin_ / (float)din : 0.f);
    aggUb[(size_t)node * 64 + lane] = (u16)f2bf(du ? (sin_ + sout_) / (float)du : 0.f);
}

// quantize h1b/u1b (bf16 [N][128]) -> uint8 per-feature-scaled, into d_out
// strided slots: row r bytes [1024r + head*128, +128).
__global__ void __launch_bounds__(256) k_quant(
        const u16* __restrict__ h1b, const u16* __restrict__ u1b,
        const float* __restrict__ maxH, const float* __restrict__ maxU,
        u8* __restrict__ ob, int N) {
    int i = blockIdx.x * blockDim.x + threadIdx.x;  // 8 elems/thread
    const int total = N * 16;
    if (i >= 2 * total) return;
    const int head = (i >= total) ? 1 : 0;
    int t = i - head * total;
    const int row = t >> 4, seg = t & 15;
    const u16* src = head ? u1b : h1b;
    const float* mx = head ? maxU : maxH;
    uint4 v = *(const uint4*)&src[(size_t)row * 128 + seg * 8];
    float4 m0 = *(const float4*)&mx[seg * 8];
    float4 m1 = *(const float4*)&mx[seg * 8 + 4];
    float rs0 = m0.x > 0.f ? 255.f / m0.x : 0.f;
    float rs1 = m0.y > 0.f ? 255.f / m0.y : 0.f;
    float rs2 = m0.z > 0.f ? 255.f / m0.z : 0.f;
    float rs3 = m0.w > 0.f ? 255.f / m0.w : 0.f;
    float rs4 = m1.x > 0.f ? 255.f / m1.x : 0.f;
    float rs5 = m1.y > 0.f ? 255.f / m1.y : 0.f;
    float rs6 = m1.z > 0.f ? 255.f / m1.z : 0.f;
    float rs7 = m1.w > 0.f ? 255.f / m1.w : 0.f;
    u32 q0 = (u32)fminf(rintf(bf_lo(v.x) * rs0), 255.f);
    u32 q1 = (u32)fminf(rintf(bf_hi(v.x) * rs1), 255.f);
    u32 q2 = (u32)fminf(rintf(bf_lo(v.y) * rs2), 255.f);
    u32 q3 = (u32)fminf(rintf(bf_hi(v.y) * rs3), 255.f);
    u32 q4 = (u32)fminf(rintf(bf_lo(v.z) * rs4), 255.f);
    u32 q5 = (u32)fminf(rintf(bf_hi(v.z) * rs5), 255.f);
    u32 q6 = (u32)fminf(rintf(bf_lo(v.w) * rs6), 255.f);
    u32 q7 = (u32)fminf(rintf(bf_hi(v.w) * rs7), 255.f);
    uint2 p;
    p.x = q0 | (q1 << 8) | (q2 << 16) | (q3 << 24);
    p.y = q4 | (q5 << 8) | (q6 << 16) | (q7 << 24);
    *(uint2*)(ob + ((size_t)row << 10) + head * 128 + seg * 8) = p;
}

// fused L1 aggregation: per node, out-adj gathers h1q AND u1q (shared idx),
// in-adj gathers u1q. v_perm packed 16-bit-field integer sums (exact; fields
// flushed every 8 values, max 2040 per field). aggH -> ws (bf16 [N][128]);
// aggU -> d_out row bytes [768,1024).
__global__ void __launch_bounds__(256) k_agg_l1_f(
        const u8* __restrict__ ob,
        const int* __restrict__ off_in, const int* __restrict__ adj_in,
        const int* __restrict__ off_out, const int* __restrict__ adj_out,
        const float* __restrict__ maxH, const float* __restrict__ maxU,
        u16* __restrict__ aggH, int n) {
    const int node = blockIdx.x * 4 + (threadIdx.x >> 6);
    const int lane = threadIdx.x & 63;
    if (node >= n) return;
    const int a0 = off_out[node], a1 = off_out[node + 1];  // out-adj: h1 + u1
    const int b0 = off_in[node], b1 = off_in[node + 1];    // in-adj: u1 only
    u32 sH0 = 0, sH1 = 0, sU0 = 0, sU1 = 0;
    const int lo2 = lane * 2;
    int j = a0;
    for (; j + 7 < a1; j += 8) {
        size_t p0 = ((size_t)adj_out[j] << 10) + lo2;
        size_t p1 = ((size_t)adj_out[j + 1] << 10) + lo2;
        size_t p2 = ((size_t)adj_out[j + 2] << 10) + lo2;
        size_t p3 = ((size_t)adj_out[j + 3] << 10) + lo2;
        size_t p4 = ((size_t)adj_out[j + 4] << 10) + lo2;
        size_t p5 = ((size_t)adj_out[j + 5] << 10) + lo2;
        size_t p6 = ((size_t)adj_out[j + 6] << 10) + lo2;
        size_t p7 = ((size_t)adj_out[j + 7] << 10) + lo2;
        u32 h0 = *(const u16*)(ob + p0), u0 = *(const u16*)(ob + p0 + 128);
        u32 h1 = *(const u16*)(ob + p1), u1 = *(const u16*)(ob + p1 + 128);
        u32 h2 = *(const u16*)(ob + p2), u2 = *(const u16*)(ob + p2 + 128);
        u32 h3 = *(const u16*)(ob + p3), u3 = *(const u16*)(ob + p3 + 128);
        u32 h4 = *(const u16*)(ob + p4), u4 = *(const u16*)(ob + p4 + 128);
        u32 h5 = *(const u16*)(ob + p5), u5 = *(const u16*)(ob + p5 + 128);
        u32 h6 = *(const u16*)(ob + p6), u6 = *(const u16*)(ob + p6 + 128);
        u32 h7 = *(const u16*)(ob + p7), u7 = *(const u16*)(ob + p7 + 128);
        u32 aH = ((sprd(h0) + sprd(h1)) + (sprd(h2) + sprd(h3))) +
                 ((sprd(h4) + sprd(h5)) + (sprd(h6) + sprd(h7)));
        u32 aU = ((sprd(u0) + sprd(u1)) + (sprd(u2) + sprd(u3))) +
                 ((sprd(u4) + sprd(u5)) + (sprd(u6) + sprd(u7)));
        sH0 += aH & 0xFFFFu; sH1 += aH >> 16;
        sU0 += aU & 0xFFFFu; sU1 += aU >> 16;
    }
    for (; j < a1; j++) {
        size_t p = ((size_t)adj_out[j] << 10) + lo2;
        u32 h = *(const u16*)(ob + p), u = *(const u16*)(ob + p + 128);
        sH0 += h & 255; sH1 += h >> 8;
        sU0 += u & 255; sU1 += u >> 8;
    }
    j = b0;
    for (; j + 7 < b1; j += 8) {
        size_t p0 = ((size_t)adj_in[j] << 10) + lo2 + 128;
        size_t p1 = ((size_t)adj_in[j + 1] << 10) + lo2 + 128;
        size_t p2 = ((size_t)adj_in[j + 2] << 10) + lo2 + 128;
        size_t p3 = ((size_t)adj_in[j + 3] << 10) + lo2 + 128;
        size_t p4 = ((size_t)adj_in[j + 4] << 10) + lo2 + 128;
        size_t p5 = ((size_t)adj_in[j + 5] << 10) + lo2 + 128;
        size_t p6 = ((size_t)adj_in[j + 6] << 10) + lo2 + 128;
        size_t p7 = ((size_t)adj_in[j + 7] << 10) + lo2 + 128;
        u32 u0 = *(const u16*)(ob + p0), u1 = *(const u16*)(ob + p1);
        u32 u2 = *(const u16*)(ob + p2), u3 = *(const u16*)(ob + p3);
        u32 u4 = *(const u16*)(ob + p4), u5 = *(const u16*)(ob + p5);
        u32 u6 = *(const u16*)(ob + p6), u7 = *(const u16*)(ob + p7);
        u32 aU = ((sprd(u0) + sprd(u1)) + (sprd(u2) + sprd(u3))) +
                 ((sprd(u4) + sprd(u5)) + (sprd(u6) + sprd(u7)));
        sU0 += aU & 0xFFFFu; sU1 += aU >> 16;
    }
    for (; j < b1; j++) {
        size_t p = ((size_t)adj_in[j] << 10) + lo2 + 128;
        u32 u = *(const u16*)(ob + p);
        sU0 += u & 255; sU1 += u >> 8;
    }
    const int degO = a1 - a0;
    const int degU = degO + (b1 - b0);
    const float invO = degO ? 1.f / (float)degO : 0.f;
    const float invU = degU ? 1.f / (float)degU : 0.f;
    float2 mh = *(const float2*)&maxH[lo2];
    float2 mu = *(const float2*)&maxU[lo2];
    const float c = 1.f / 255.f;
    u32 pH = f2bf((float)sH0 * mh.x * c * invO) |
             (f2bf((float)sH1 * mh.y * c * invO) << 16);
    u32 pU = f2bf((float)sU0 * mu.x * c * invU) |
             (f2bf((float)sU1 * mu.y * c * invU) << 16);
    *(u32*)&aggH[(size_t)node * 128 + lo2] = pH;
    *(u32*)((u8*)ob + ((size_t)node << 10) + 768 + lane * 4) = pU;
}

// MFMA dual-GEMM tile: wave = 16 rows x 128 cols. W1/W2 staged in LDS once
// per block (shared by all waves), XOR-swizzled byte ^= (row&7)<<4 on write
// AND read to break the stride-(K*2)B bank conflict (guide G4/T2 pattern).
// A/B frags from global. Layouts (gfx950 16x16x32 bf16): A row=lane&15,
// k=8*(lane>>4)+j; C/D col=lane&15, row=(lane>>4)*4+reg.
// OUT_BF16=1: bf16 store + per-column max. OUT_BF16=0: NT fp32 store.
template <int KC, int OUT_BF16>  // KC = K/32
__device__ __forceinline__ void gemm_tile(
        const u16* __restrict__ A, int lda,
        const u16* __restrict__ B, int ldb,
        const u16* __restrict__ W1, const u16* __restrict__ W2,
        u8* lds1, u8* lds2, int* lmax,
        const float* __restrict__ bias,
        float* __restrict__ OutF, int ldo, u16* __restrict__ OutB,
        int* __restrict__ colmax, int n, int r0, int nthreads) {
    constexpr int K = KC * 32;
    constexpr int RS = K * 2;        // W row stride in bytes
    constexpr int WB = 128 * RS;     // bytes per W matrix
    const int tid = threadIdx.x;
    const int lane = tid & 63;

    // stage W1/W2 -> LDS (swizzled); coalesced 16B chunks per thread
    for (int i = tid * 16; i < WB; i += nthreads * 16) {
        const int row = i / RS;
        const int swz = i ^ ((row & 7) << 4);
        *(uint4*)(lds1 + swz) = *(const uint4*)((const u8*)W1 + i);
        *(uint4*)(lds2 + swz) = *(const uint4*)((const u8*)W2 + i);
    }
    if (OUT_BF16 && tid < 128) lmax[tid] = 0;
    __syncthreads();

    const int arow = r0 + (lane & 15);
    const int crow = (arow < n) ? arow : n - 1;
    const int kof = (lane >> 4) * 8;
    const int kofb = kof * 2;

    bf16x8 a1[KC], a2[KC];
#pragma unroll
    for (int kc = 0; kc < KC; kc++) {
        a1[kc] = *(const bf16x8*)&A[(size_t)crow * lda + kc * 32 + kof];
        a2[kc] = *(const bf16x8*)&B[(size_t)crow * ldb + kc * 32 + kof];
    }
    const int wr = lane & 15;
    const int rbase = r0 + (lane >> 4) * 4;
#pragma unroll
    for (int c = 0; c < 8; c++) {
        f32x4 acc = {0.f, 0.f, 0.f, 0.f};
        const int wrow = c * 16 + wr;
        const int wbase = wrow * RS + kofb;
        const int rsw = (wrow & 7) << 4;
#pragma unroll
        for (int kc = 0; kc < KC; kc++) {
            const int bo = (wbase + kc * 64) ^ rsw;
            acc = __builtin_amdgcn_mfma_f32_16x16x32_bf16(
                a1[kc], *(const bf16x8*)(lds1 + bo), acc, 0, 0, 0);
            acc = __builtin_amdgcn_mfma_f32_16x16x32_bf16(
                a2[kc], *(const bf16x8*)(lds2 + bo), acc, 0, 0, 0);
        }
        const int col = c * 16 + wr;
        const float bv = bias[col];
        float cmax = 0.f;
#pragma unroll
        for (int r = 0; r < 4; r++) {
            const int row = rbase + r;
            if (row < n) {
                float v = acc[r] + bv;
                if (OUT_BF16) {
                    v = fmaxf(v, 0.f);  // relu (L0 layers)
                    cmax = fmaxf(cmax, v);
                    OutB[(size_t)row * 128 + col] = (u16)f2bf(v);
                } else {
                    __builtin_nontemporal_store(v, &OutF[(size_t)row * ldo + col]);
                }
            }
        }
        if (OUT_BF16) atomicMax(&lmax[col], __float_as_int(cmax));
    }
    if (OUT_BF16) {
        __syncthreads();
        if (tid < 128) atomicMax(&colmax[tid], lmax[tid]);
    }
}

// fused L0 gemm: 512 thr (8 waves x 16 rows = 128 rows/block); head = upper
// half of grid. LDS: 2 x 16 KB W + lmax.
__global__ void __launch_bounds__(512) k_gemm_l0_fused(
        const u16* __restrict__ xb,
        const u16* __restrict__ agg0b, const u16* __restrict__ aggUb,
        const u16* __restrict__ Wsb0, const u16* __restrict__ Wnb0,
        const float* __restrict__ b0,
        u16* __restrict__ h1b, u16* __restrict__ u1b,
        int* __restrict__ maxH, int* __restrict__ maxU, int n, int nblk) {
    __shared__ u8 lds1[128 * 64 * 2], lds2[128 * 64 * 2];
    __shared__ int lmax[128];
    const int head = (blockIdx.x >= nblk) ? 1 : 0;
    const int blk = blockIdx.x - head * nblk;
    const int r0 = blk * 128 + (threadIdx.x >> 6) * 16;
    gemm_tile<2, 1>(xb, 64, head ? aggUb : agg0b, 64,
                    Wsb0 + head * 128 * 64, Wnb0 + head * 128 * 64,
                    lds1, lds2, lmax,
                    b0 + head * 128, (float*)nullptr, 0,
                    head ? u1b : h1b, head ? maxU : maxH, n, r0, 512);
}

// fused L1 gemm: 512 thr, 128 rows/block. head0 A=h1b B=aggH(ws, ldb=128);
// head1 A=u1b B=aggU in d_out rows (u16 offset 384, ldb=512). Safe: head0
// writes out bytes [0,512) (disjoint from aggU at [768,1024)); head1 reads
// its B rows into registers before storing bytes [512,1024) (row-disjoint
// across waves). LDS: 2 x 32 KB W.
__global__ void __launch_bounds__(512) k_gemm_l1_fused(
        const u16* __restrict__ h1b, const u16* __restrict__ u1b,
        const u16* __restrict__ aggH, const u16* __restrict__ aggU,
        const u16* __restrict__ Wsb1, const u16* __restrict__ Wnb1,
        const float* __restrict__ b1,
        float* __restrict__ out, int n, int nblk) {
    __shared__ u8 lds1[128 * 128 * 2], lds2[128 * 128 * 2];
    const int head = (blockIdx.x >= nblk) ? 1 : 0;
    const int blk = blockIdx.x - head * nblk;
    const int r0 = blk * 128 + (threadIdx.x >> 6) * 16;
    if (head == 0) {
        gemm_tile<4, 0>(h1b, 128, aggH, 128, Wsb1, Wnb1, lds1, lds2, (int*)nullptr,
                        b1, out, 256, (u16*)nullptr, (int*)nullptr, n, r0, 512);
    } else {
        gemm_tile<4, 0>(u1b, 128, aggU, 512, Wsb1 + 128 * 128, Wnb1 + 128 * 128,
                        lds1, lds2, (int*)nullptr, b1 + 128, out + 128, 256,
                        (u16*)nullptr, (int*)nullptr, n, r0, 512);
    }
}

extern "C" void kernel_launch(void* const* d_in, const int* in_sizes, int n_in,
                              void* d_out, int out_size, void* d_ws, size_t ws_size,
                              hipStream_t stream) {
    const float* x = (const float*)d_in[0];
    const int* src = (const int*)d_in[1];
    const int* dst = (const int*)d_in[2];
    const float* Wn0 = (const float*)d_in[3];
    const float* Ws0 = (const float*)d_in[4];
    const float* b0 = (const float*)d_in[5];
    const float* Wn1 = (const float*)d_in[6];
    const float* Ws1 = (const float*)d_in[7];
    const float* b1 = (const float*)d_in[8];

    const int N = in_sizes[0] / 64;
    const int E = in_sizes[1];
    float* out = (float*)d_out;
    const int NB = (N + 255) >> 8;  // buckets of 256 nodes (must be <= 512)

    // ---- workspace layout (~91 MB) ----
    char* w = (char*)d_ws;
    size_t o = 0;
    auto alloc = [&](size_t bytes) -> void* {
        o = (o + 255) & ~(size_t)255;
        void* p = w + o;
        o += bytes;
        return p;
    };
    int* off_in = (int*)alloc((size_t)(N + 1) * 4);
    int* off_out = (int*)alloc((size_t)(N + 1) * 4);
    int* cntD = (int*)alloc(512 * 4);
    int* cntS = (int*)alloc(512 * 4);
    int* curD = (int*)alloc(512 * 4);
    int* curS = (int*)alloc(512 * 4);
    int* bbaseD = (int*)alloc(513 * 4);
    int* bbaseS = (int*)alloc(513 * 4);
    float* maxH = (float*)alloc(128 * 4);
    float* maxU = (float*)alloc(128 * 4);
    int* adj_in = (int*)alloc((size_t)E * 4);
    int* adj_out = (int*)alloc((size_t)E * 4);
    u16* AGGb = (u16*)alloc((size_t)N * 128 * 2);  // L0 agg 2x[N][64]; L1 aggH
    u16* h1b = (u16*)alloc((size_t)N * 128 * 2);
    u16* u1b = (u16*)alloc((size_t)N * 128 * 2);
    u16* Wsb0 = (u16*)alloc(2 * 128 * 64 * 2);
    u16* Wnb0 = (u16*)alloc(2 * 128 * 64 * 2);
    u16* Wsb1 = (u16*)alloc(2 * 128 * 128 * 2);
    u16* Wnb1 = (u16*)alloc(2 * 128 * 128 * 2);
    (void)ws_size;

    // pair arrays alias h1b/u1b (dead until the L0 gemm runs, after pass D)
    u32* pairsD = (u32*)h1b;
    u32* pairsS = (u32*)u1b;
    // d_out scratch, time-phased:
    //  phase A (prep..L0): xb bf16 @0 (12.8M), xq fp8 @16M (6.4M)
    //  phase B (quant..L1): per-row 1KB slots: h1q[0,128) u1q[128,256)
    //                       aggU[768,1024)
    u16* xb = (u16*)d_out;
    u8* xq = (u8*)d_out + (16 << 20);
    u8* ob = (u8*)d_out;

    const int n4 = N * 64 / 4;
    const int edgeBlocks = ((E + 7) / 8 + 255) / 256;

    // ---- fused prep ----
    k_prep<<<(n4 + 98304 + 255) / 256, 256, 0, stream>>>(
        x, xb, xq, n4, cntD, (int*)maxH, Ws0, Wn0, Ws1, Wn1, Wsb0, Wnb0, Wsb1, Wnb1);

    // ---- CSR build via bucketed counting sort ----
    k_bincnt<<<edgeBlocks, 256, 0, stream>>>(src, dst, cntD, cntS, E, NB);
    k_binscan<<<1, 512, 0, stream>>>(cntD, cntS, bbaseD, bbaseS, curD, curS,
                                     off_in, off_out, NB, N, E);
    k_binscatter<<<edgeBlocks, 256, 0, stream>>>(src, dst, curD, curS, pairsD, pairsS, E, NB);
    k_bucket_csr<<<2 * NB, 256, 0, stream>>>(pairsD, pairsS, bbaseD, bbaseS,
                                             off_in, adj_in, off_out, adj_out, N);

    const int nodeBlocks = (N + 3) / 4;
    const int gemmBlocks128 = (N + 127) / 128;

    // ---- layer 0 ----
    u16* agg0b = AGGb;                    // [N][64]
    u16* aggUb = AGGb + (size_t)N * 64;   // [N][64]
    k_agg_l0_q<<<nodeBlocks, 256, 0, stream>>>(xq, off_in, adj_in, off_out, adj_out,
                                               agg0b, aggUb, N);
    k_gemm_l0_fused<<<2 * gemmBlocks128, 512, 0, stream>>>(
        xb, agg0b, aggUb, Wsb0, Wnb0, b0, h1b, u1b, (int*)maxH, (int*)maxU,
        N, gemmBlocks128);

    // ---- quantize h1/u1 to per-feature uint8 into d_out slots ----
    k_quant<<<(2 * N * 16 + 255) / 256, 256, 0, stream>>>(h1b, u1b, maxH, maxU, ob, N);

    // ---- fused L1 aggregation (aggH -> AGGb ws; aggU -> d_out rows) ----
    k_agg_l1_f<<<nodeBlocks, 256, 0, stream>>>(ob, off_in, adj_in, off_out, adj_out,
                                               maxH, maxU, AGGb, N);

    // ---- fused L1 gemm (both heads, one dispatch, W in LDS) ----
    k_gemm_l1_fused<<<2 * gemmBlocks128, 512, 0, stream>>>(
        h1b, u1b, AGGb, (const u16*)d_out + 384, Wsb1, Wnb1, b1, out, N, gemmBlocks128);
}

// Round 12
// 395.661 us; speedup vs baseline: 1.6568x; 1.0993x over previous
//
#include <hip/hip_runtime.h>
#include <hip/hip_fp8.h>

// ---------------------------------------------------------------------------
// SAGEMultiSwitchModel: 2 heads x 2 SAGE layers on N=100k nodes, E=1.6M edges.
// head0 dirs "OI", head1 "UU". Layer: act([h|seg_mean(h)] @ [Ws|Wn]^T + b).
// R1: spill-free gemm. R2: bf16 gather tables. R4: bucketed-sort CSR build.
// R5: MFMA gemms. R6: fp8 x-table for L0 agg. R9/R10: uint8 L1 tables +
// fused perm-packed int-sum L1 agg. R11: W staged in LDS (gemms were 4%
// MfmaUtil from per-wave W re-reads).
// R12: agg_l0 was issue-bound (0.92 of 2.55 TB/s miss plateau, 1-byte loads):
//      now 4 edges/wave-load (lane g=lane>>4 handles edge j+g, u32 = 4 fp8
//      features), cvt_f32_fp8 byte-select decode, shfl_xor(16,32) butterfly
//      merge, group-0 coalesced write. ~6 -> ~2.5 inst/value.
// d_out row r (1024B): [0,128)=h1q [128,256)=u1q [768,1024)=aggU.
// ---------------------------------------------------------------------------

typedef unsigned short u16;
typedef unsigned int u32;
typedef unsigned char u8;
typedef __bf16 bf16x8 __attribute__((ext_vector_type(8)));
typedef float f32x4 __attribute__((ext_vector_type(4)));

__device__ __forceinline__ u32 f2bf(float f) {  // RNE float->bf16 (low 16 bits)
    u32 u = __float_as_uint(f);
    return (u + 0x7fffu + ((u >> 16) & 1u)) >> 16;
}
__device__ __forceinline__ float bf_lo(u32 v) { return __uint_as_float(v << 16); }
__device__ __forceinline__ float bf_hi(u32 v) { return __uint_as_float(v & 0xffff0000u); }
__device__ __forceinline__ u8 f2q(float f) {  // float -> fp8 e4m3 (OCP)
    __hip_fp8_e4m3 t(f);
    return *(u8*)&t;
}
// spread byte pair (b0,b1) of v into 16-bit fields: b0 | (b1<<16). one v_perm.
__device__ __forceinline__ u32 sprd(u32 v) {
    return __builtin_amdgcn_perm(0u, v, 0x04010400u);
}
// accumulate 4 fp8 bytes of v into float4 (v_cvt_f32_fp8 with byte select)
__device__ __forceinline__ void acc4(float4& s, u32 v) {
    s.x += __builtin_amdgcn_cvt_f32_fp8(v, 0);
    s.y += __builtin_amdgcn_cvt_f32_fp8(v, 1);
    s.z += __builtin_amdgcn_cvt_f32_fp8(v, 2);
    s.w += __builtin_amdgcn_cvt_f32_fp8(v, 3);
}

// fused prep: zero cnt[1024]+maxs[256]; x -> bf16 xb AND fp8 xq; weights bf16
__global__ void k_prep(const float* __restrict__ x, u16* __restrict__ xb,
                       u8* __restrict__ xq, int n4, int* __restrict__ cntzero,
                       int* __restrict__ maxzero,
                       const float* __restrict__ Ws0, const float* __restrict__ Wn0,
                       const float* __restrict__ Ws1, const float* __restrict__ Wn1,
                       u16* __restrict__ Wsb0, u16* __restrict__ Wnb0,
                       u16* __restrict__ Wsb1, u16* __restrict__ Wnb1) {
    int i = blockIdx.x * blockDim.x + threadIdx.x;
    if (i < 1024) cntzero[i] = 0;
    if (i < 256) maxzero[i] = 0;
    if (i < n4) {
        float4 v = *(const float4*)&x[(size_t)i * 4];
        u32 p0 = f2bf(v.x) | (f2bf(v.y) << 16);
        u32 p1 = f2bf(v.z) | (f2bf(v.w) << 16);
        *(uint2*)&xb[(size_t)i * 4] = make_uint2(p0, p1);
        u32 q = (u32)f2q(v.x) | ((u32)f2q(v.y) << 8) |
                ((u32)f2q(v.z) << 16) | ((u32)f2q(v.w) << 24);
        *(u32*)&xq[(size_t)i * 4] = q;
        return;
    }
    int t = i - n4;
    if (t < 16384) Wsb0[t] = (u16)f2bf(Ws0[t]);
    else if (t < 32768) Wnb0[t - 16384] = (u16)f2bf(Wn0[t - 16384]);
    else if (t < 65536) Wsb1[t - 32768] = (u16)f2bf(Ws1[t - 32768]);
    else if (t < 98304) Wnb1[t - 65536] = (u16)f2bf(Wn1[t - 65536]);
}

// ---- bucketed CSR build: NPB=256 nodes/bucket, bucket = node>>8 ----

__global__ void __launch_bounds__(256) k_bincnt(
        const int* __restrict__ src, const int* __restrict__ dst,
        int* cntD, int* cntS, int E, int NB) {
    __shared__ int hD[512], hS[512];
    const int tid = threadIdx.x;
    for (int i = tid; i < NB; i += 256) { hD[i] = 0; hS[i] = 0; }
    __syncthreads();
    const int base = (blockIdx.x * 256 + tid) * 8;
#pragma unroll
    for (int i = 0; i < 8; i++) {
        if (base + i < E) {
            atomicAdd(&hD[dst[base + i] >> 8], 1);
            atomicAdd(&hS[src[base + i] >> 8], 1);
        }
    }
    __syncthreads();
    for (int i = tid; i < NB; i += 256) {
        if (hD[i]) atomicAdd(&cntD[i], hD[i]);
        if (hS[i]) atomicAdd(&cntS[i], hS[i]);
    }
}

__global__ void __launch_bounds__(512) k_binscan(
        const int* __restrict__ cntD, const int* __restrict__ cntS,
        int* bbaseD, int* bbaseS, int* curD, int* curS,
        int* off_in, int* off_out, int NB, int N, int E) {
    __shared__ int ts[512];
    const int tid = threadIdx.x;
    int v = (tid < NB) ? cntD[tid] : 0;
    ts[tid] = v;
    __syncthreads();
    for (int ofs = 1; ofs < 512; ofs <<= 1) {
        int t = (tid >= ofs) ? ts[tid - ofs] : 0;
        __syncthreads();
        ts[tid] += t;
        __syncthreads();
    }
    int ex = ts[tid] - v;
    if (tid < NB) { bbaseD[tid] = ex; curD[tid] = ex; }
    if (tid == NB - 1) bbaseD[NB] = ex + v;
    __syncthreads();
    v = (tid < NB) ? cntS[tid] : 0;
    ts[tid] = v;
    __syncthreads();
    for (int ofs = 1; ofs < 512; ofs <<= 1) {
        int t = (tid >= ofs) ? ts[tid - ofs] : 0;
        __syncthreads();
        ts[tid] += t;
        __syncthreads();
    }
    ex = ts[tid] - v;
    if (tid < NB) { bbaseS[tid] = ex; curS[tid] = ex; }
    if (tid == NB - 1) bbaseS[NB] = ex + v;
    if (tid == 0) { off_in[N] = E; off_out[N] = E; }
}

__global__ void __launch_bounds__(256) k_binscatter(
        const int* __restrict__ src, const int* __restrict__ dst,
        int* curD, int* curS, u32* __restrict__ pairsD, u32* __restrict__ pairsS,
        int E, int NB) {
    __shared__ int hD[512], hS[512], bD[512], bS[512];
    const int tid = threadIdx.x;
    for (int i = tid; i < NB; i += 256) { hD[i] = 0; hS[i] = 0; }
    __syncthreads();
    const int base = (blockIdx.x * 256 + tid) * 8;
    int sv[8], dv[8], rD[8], rS[8];
#pragma unroll
    for (int i = 0; i < 8; i++) {
        if (base + i < E) {
            sv[i] = src[base + i];
            dv[i] = dst[base + i];
            rD[i] = atomicAdd(&hD[dv[i] >> 8], 1);
            rS[i] = atomicAdd(&hS[sv[i] >> 8], 1);
        }
    }
    __syncthreads();
    for (int i = tid; i < NB; i += 256) {
        bD[i] = hD[i] ? atomicAdd(&curD[i], hD[i]) : 0;
        bS[i] = hS[i] ? atomicAdd(&curS[i], hS[i]) : 0;
    }
    __syncthreads();
#pragma unroll
    for (int i = 0; i < 8; i++) {
        if (base + i < E) {
            pairsD[bD[dv[i] >> 8] + rD[i]] = ((u32)(dv[i] & 255) << 24) | (u32)sv[i];
            pairsS[bS[sv[i] >> 8] + rS[i]] = ((u32)(sv[i] & 255) << 24) | (u32)dv[i];
        }
    }
}

__global__ void __launch_bounds__(256) k_bucket_csr(
        const u32* __restrict__ pairsD, const u32* __restrict__ pairsS,
        const int* __restrict__ bbaseD, const int* __restrict__ bbaseS,
        int* __restrict__ off_in, int* __restrict__ adj_in,
        int* __restrict__ off_out, int* __restrict__ adj_out, int N) {
    __shared__ int cnt[256], cur[256], ts[256];
    const int b = blockIdx.x >> 1;
    const int arr = blockIdx.x & 1;
    const u32* pairs = arr ? pairsS : pairsD;
    const int* bbase = arr ? bbaseS : bbaseD;
    int* off = arr ? off_out : off_in;
    int* adj = arr ? adj_out : adj_in;
    const int e0 = bbase[b], e1 = bbase[b + 1];
    const int tid = threadIdx.x;
    cnt[tid] = 0;
    __syncthreads();
    for (int e = e0 + tid; e < e1; e += 256) atomicAdd(&cnt[pairs[e] >> 24], 1);
    __syncthreads();
    int v = cnt[tid];
    ts[tid] = v;
    __syncthreads();
    for (int ofs = 1; ofs < 256; ofs <<= 1) {
        int t = (tid >= ofs) ? ts[tid - ofs] : 0;
        __syncthreads();
        ts[tid] += t;
        __syncthreads();
    }
    const int ex = ts[tid] - v;
    const int n = b * 256 + tid;
    if (n < N) off[n] = e0 + ex;
    cur[tid] = e0 + ex;
    __syncthreads();
    for (int e = e0 + tid; e < e1; e += 256) {
        u32 p = pairs[e];
        int w = atomicAdd(&cur[p >> 24], 1);
        adj[w] = (int)(p & 0xFFFFFFu);
    }
}

// layer-0 aggregation: fp8 gather, 4 edges per wave-load. lane = (g=lane>>4,
// p=lane&15): lane loads u32 (features 4p..4p+3) of edge j+g. Partial float4
// sums merged by shfl_xor(16,32) butterfly; group 0 writes coalesced bf16.
__global__ void __launch_bounds__(256) k_agg_l0_q(
        const u8* __restrict__ xq,
        const int* __restrict__ off_in, const int* __restrict__ adj_in,
        const int* __restrict__ off_out, const int* __restrict__ adj_out,
        u16* __restrict__ agg0b, u16* __restrict__ aggUb, int n) {
    const int node = blockIdx.x * 4 + (threadIdx.x >> 6);
    const int lane = threadIdx.x & 63;
    if (node >= n) return;
    const int g = lane >> 4;          // edge slot within group of 4
    const int p = (lane & 15) * 4;    // feature base (bytes)
    const int a0 = off_in[node], a1 = off_in[node + 1];
    const int b0 = off_out[node], b1 = off_out[node + 1];
    float4 si = {0.f, 0.f, 0.f, 0.f}, so = {0.f, 0.f, 0.f, 0.f};
    int j = a0;
    for (; j + 15 < a1; j += 16) {
        int i0 = adj_in[j + g], i1 = adj_in[j + 4 + g];
        int i2 = adj_in[j + 8 + g], i3 = adj_in[j + 12 + g];
        u32 v0 = *(const u32*)&xq[(size_t)i0 * 64 + p];
        u32 v1 = *(const u32*)&xq[(size_t)i1 * 64 + p];
        u32 v2 = *(const u32*)&xq[(size_t)i2 * 64 + p];
        u32 v3 = *(const u32*)&xq[(size_t)i3 * 64 + p];
        acc4(si, v0); acc4(si, v1); acc4(si, v2); acc4(si, v3);
    }
    for (; j + 3 < a1; j += 4) {
        int i0 = adj_in[j + g];
        u32 v0 = *(const u32*)&xq[(size_t)i0 * 64 + p];
        acc4(si, v0);
    }
    if (j < a1 && g < a1 - j) {
        int i0 = adj_in[j + g];
        u32 v0 = *(const u32*)&xq[(size_t)i0 * 64 + p];
        acc4(si, v0);
    }
    j = b0;
    for (; j + 15 < b1; j += 16) {
        int i0 = adj_out[j + g], i1 = adj_out[j + 4 + g];
        int i2 = adj_out[j + 8 + g], i3 = adj_out[j + 12 + g];
        u32 v0 = *(const u32*)&xq[(size_t)i0 * 64 + p];
        u32 v1 = *(const u32*)&xq[(size_t)i1 * 64 + p];
        u32 v2 = *(const u32*)&xq[(size_t)i2 * 64 + p];
        u32 v3 = *(const u32*)&xq[(size_t)i3 * 64 + p];
        acc4(so, v0); acc4(so, v1); acc4(so, v2); acc4(so, v3);
    }
    for (; j + 3 < b1; j += 4) {
        int i0 = adj_out[j + g];
        u32 v0 = *(const u32*)&xq[(size_t)i0 * 64 + p];
        acc4(so, v0);
    }
    if (j < b1 && g < b1 - j) {
        int i0 = adj_out[j + g];
        u32 v0 = *(const u32*)&xq[(size_t)i0 * 64 + p];
        acc4(so, v0);
    }
    // merge the 4 edge-groups (butterfly over lane bits 4,5)
#pragma unroll
    for (int ofs = 16; ofs < 64; ofs <<= 1) {
        si.x += __shfl_xor(si.x, ofs);
        si.y += __shfl_xor(si.y, ofs);
        si.z += __shfl_xor(si.z, ofs);
        si.w += __shfl_xor(si.w, ofs);
        so.x += __shfl_xor(so.x, ofs);
        so.y += __shfl_xor(so.y, ofs);
        so.z += __shfl_xor(so.z, ofs);
        so.w += __shfl_xor(so.w, ofs);
    }
    if (g == 0) {
        const int din = a1 - a0, dout = b1 - b0;
        const int du = din + dout;
        const float fi = din ? 1.f / (float)din : 0.f;
        const float fu = du ? 1.f / (float)du : 0.f;
        uint2 q0, qU;
        q0.x = f2bf(si.x * fi) | (f2bf(si.y * fi) << 16);
        q0.y = f2bf(si.z * fi) | (f2bf(si.w * fi) << 16);
        qU.x = f2bf((si.x + so.x) * fu) | (f2bf((si.y + so.y) * fu) << 16);
        qU.y = f2bf((si.z + so.z) * fu) | (f2bf((si.w + so.w) * fu) << 16);
        *(uint2*)&agg0b[(size_t)node * 64 + p] = q0;
        *(uint2*)&aggUb[(size_t)node * 64 + p] = qU;
    }
}

// quantize h1b/u1b (bf16 [N][128]) -> uint8 per-feature-scaled, into d_out
// strided slots: row r bytes [1024r + head*128, +128).
__global__ void __launch_bounds__(256) k_quant(
        const u16* __restrict__ h1b, const u16* __restrict__ u1b,
        const float* __restrict__ maxH, const float* __restrict__ maxU,
        u8* __restrict__ ob, int N) {
    int i = blockIdx.x * blockDim.x + threadIdx.x;  // 8 elems/thread
    const int total = N * 16;
    if (i >= 2 * total) return;
    const int head = (i >= total) ? 1 : 0;
    int t = i - head * total;
    const int row = t >> 4, seg = t & 15;
    const u16* src = head ? u1b : h1b;
    const float* mx = head ? maxU : maxH;
    uint4 v = *(const uint4*)&src[(size_t)row * 128 + seg * 8];
    float4 m0 = *(const float4*)&mx[seg * 8];
    float4 m1 = *(const float4*)&mx[seg * 8 + 4];
    float rs0 = m0.x > 0.f ? 255.f / m0.x : 0.f;
    float rs1 = m0.y > 0.f ? 255.f / m0.y : 0.f;
    float rs2 = m0.z > 0.f ? 255.f / m0.z : 0.f;
    float rs3 = m0.w > 0.f ? 255.f / m0.w : 0.f;
    float rs4 = m1.x > 0.f ? 255.f / m1.x : 0.f;
    float rs5 = m1.y > 0.f ? 255.f / m1.y : 0.f;
    float rs6 = m1.z > 0.f ? 255.f / m1.z : 0.f;
    float rs7 = m1.w > 0.f ? 255.f / m1.w : 0.f;
    u32 q0 = (u32)fminf(rintf(bf_lo(v.x) * rs0), 255.f);
    u32 q1 = (u32)fminf(rintf(bf_hi(v.x) * rs1), 255.f);
    u32 q2 = (u32)fminf(rintf(bf_lo(v.y) * rs2), 255.f);
    u32 q3 = (u32)fminf(rintf(bf_hi(v.y) * rs3), 255.f);
    u32 q4 = (u32)fminf(rintf(bf_lo(v.z) * rs4), 255.f);
    u32 q5 = (u32)fminf(rintf(bf_hi(v.z) * rs5), 255.f);
    u32 q6 = (u32)fminf(rintf(bf_lo(v.w) * rs6), 255.f);
    u32 q7 = (u32)fminf(rintf(bf_hi(v.w) * rs7), 255.f);
    uint2 p;
    p.x = q0 | (q1 << 8) | (q2 << 16) | (q3 << 24);
    p.y = q4 | (q5 << 8) | (q6 << 16) | (q7 << 24);
    *(uint2*)(ob + ((size_t)row << 10) + head * 128 + seg * 8) = p;
}

// fused L1 aggregation: per node, out-adj gathers h1q AND u1q (shared idx),
// in-adj gathers u1q. v_perm packed 16-bit-field integer sums (exact; fields
// flushed every 8 values, max 2040 per field). aggH -> ws (bf16 [N][128]);
// aggU -> d_out row bytes [768,1024).
__global__ void __launch_bounds__(256) k_agg_l1_f(
        const u8* __restrict__ ob,
        const int* __restrict__ off_in, const int* __restrict__ adj_in,
        const int* __restrict__ off_out, const int* __restrict__ adj_out,
        const float* __restrict__ maxH, const float* __restrict__ maxU,
        u16* __restrict__ aggH, int n) {
    const int node = blockIdx.x * 4 + (threadIdx.x >> 6);
    const int lane = threadIdx.x & 63;
    if (node >= n) return;
    const int a0 = off_out[node], a1 = off_out[node + 1];  // out-adj: h1 + u1
    const int b0 = off_in[node], b1 = off_in[node + 1];    // in-adj: u1 only
    u32 sH0 = 0, sH1 = 0, sU0 = 0, sU1 = 0;
    const int lo2 = lane * 2;
    int j = a0;
    for (; j + 7 < a1; j += 8) {
        size_t p0 = ((size_t)adj_out[j] << 10) + lo2;
        size_t p1 = ((size_t)adj_out[j + 1] << 10) + lo2;
        size_t p2 = ((size_t)adj_out[j + 2] << 10) + lo2;
        size_t p3 = ((size_t)adj_out[j + 3] << 10) + lo2;
        size_t p4 = ((size_t)adj_out[j + 4] << 10) + lo2;
        size_t p5 = ((size_t)adj_out[j + 5] << 10) + lo2;
        size_t p6 = ((size_t)adj_out[j + 6] << 10) + lo2;
        size_t p7 = ((size_t)adj_out[j + 7] << 10) + lo2;
        u32 h0 = *(const u16*)(ob + p0), u0 = *(const u16*)(ob + p0 + 128);
        u32 h1 = *(const u16*)(ob + p1), u1 = *(const u16*)(ob + p1 + 128);
        u32 h2 = *(const u16*)(ob + p2), u2 = *(const u16*)(ob + p2 + 128);
        u32 h3 = *(const u16*)(ob + p3), u3 = *(const u16*)(ob + p3 + 128);
        u32 h4 = *(const u16*)(ob + p4), u4 = *(const u16*)(ob + p4 + 128);
        u32 h5 = *(const u16*)(ob + p5), u5 = *(const u16*)(ob + p5 + 128);
        u32 h6 = *(const u16*)(ob + p6), u6 = *(const u16*)(ob + p6 + 128);
        u32 h7 = *(const u16*)(ob + p7), u7 = *(const u16*)(ob + p7 + 128);
        u32 aH = ((sprd(h0) + sprd(h1)) + (sprd(h2) + sprd(h3))) +
                 ((sprd(h4) + sprd(h5)) + (sprd(h6) + sprd(h7)));
        u32 aU = ((sprd(u0) + sprd(u1)) + (sprd(u2) + sprd(u3))) +
                 ((sprd(u4) + sprd(u5)) + (sprd(u6) + sprd(u7)));
        sH0 += aH & 0xFFFFu; sH1 += aH >> 16;
        sU0 += aU & 0xFFFFu; sU1 += aU >> 16;
    }
    for (; j < a1; j++) {
        size_t p = ((size_t)adj_out[j] << 10) + lo2;
        u32 h = *(const u16*)(ob + p), u = *(const u16*)(ob + p + 128);
        sH0 += h & 255; sH1 += h >> 8;
        sU0 += u & 255; sU1 += u >> 8;
    }
    j = b0;
    for (; j + 7 < b1; j += 8) {
        size_t p0 = ((size_t)adj_in[j] << 10) + lo2 + 128;
        size_t p1 = ((size_t)adj_in[j + 1] << 10) + lo2 + 128;
        size_t p2 = ((size_t)adj_in[j + 2] << 10) + lo2 + 128;
        size_t p3 = ((size_t)adj_in[j + 3] << 10) + lo2 + 128;
        size_t p4 = ((size_t)adj_in[j + 4] << 10) + lo2 + 128;
        size_t p5 = ((size_t)adj_in[j + 5] << 10) + lo2 + 128;
        size_t p6 = ((size_t)adj_in[j + 6] << 10) + lo2 + 128;
        size_t p7 = ((size_t)adj_in[j + 7] << 10) + lo2 + 128;
        u32 u0 = *(const u16*)(ob + p0), u1 = *(const u16*)(ob + p1);
        u32 u2 = *(const u16*)(ob + p2), u3 = *(const u16*)(ob + p3);
        u32 u4 = *(const u16*)(ob + p4), u5 = *(const u16*)(ob + p5);
        u32 u6 = *(const u16*)(ob + p6), u7 = *(const u16*)(ob + p7);
        u32 aU = ((sprd(u0) + sprd(u1)) + (sprd(u2) + sprd(u3))) +
                 ((sprd(u4) + sprd(u5)) + (sprd(u6) + sprd(u7)));
        sU0 += aU & 0xFFFFu; sU1 += aU >> 16;
    }
    for (; j < b1; j++) {
        size_t p = ((size_t)adj_in[j] << 10) + lo2 + 128;
        u32 u = *(const u16*)(ob + p);
        sU0 += u & 255; sU1 += u >> 8;
    }
    const int degO = a1 - a0;
    const int degU = degO + (b1 - b0);
    const float invO = degO ? 1.f / (float)degO : 0.f;
    const float invU = degU ? 1.f / (float)degU : 0.f;
    float2 mh = *(const float2*)&maxH[lo2];
    float2 mu = *(const float2*)&maxU[lo2];
    const float c = 1.f / 255.f;
    u32 pH = f2bf((float)sH0 * mh.x * c * invO) |
             (f2bf((float)sH1 * mh.y * c * invO) << 16);
    u32 pU = f2bf((float)sU0 * mu.x * c * invU) |
             (f2bf((float)sU1 * mu.y * c * invU) << 16);
    *(u32*)&aggH[(size_t)node * 128 + lo2] = pH;
    *(u32*)((u8*)ob + ((size_t)node << 10) + 768 + lane * 4) = pU;
}

// MFMA dual-GEMM tile: wave = 16 rows x 128 cols. W1/W2 staged in LDS once
// per block (shared by all waves), XOR-swizzled byte ^= (row&7)<<4 on write
// AND read to break the stride-(K*2)B bank conflict (guide G4/T2 pattern).
// A/B frags from global. Layouts (gfx950 16x16x32 bf16): A row=lane&15,
// k=8*(lane>>4)+j; C/D col=lane&15, row=(lane>>4)*4+reg.
// OUT_BF16=1: bf16 store + per-column max. OUT_BF16=0: NT fp32 store.
template <int KC, int OUT_BF16>  // KC = K/32
__device__ __forceinline__ void gemm_tile(
        const u16* __restrict__ A, int lda,
        const u16* __restrict__ B, int ldb,
        const u16* __restrict__ W1, const u16* __restrict__ W2,
        u8* lds1, u8* lds2, int* lmax,
        const float* __restrict__ bias,
        float* __restrict__ OutF, int ldo, u16* __restrict__ OutB,
        int* __restrict__ colmax, int n, int r0, int nthreads) {
    constexpr int K = KC * 32;
    constexpr int RS = K * 2;        // W row stride in bytes
    constexpr int WB = 128 * RS;     // bytes per W matrix
    const int tid = threadIdx.x;
    const int lane = tid & 63;

    // stage W1/W2 -> LDS (swizzled); coalesced 16B chunks per thread
    for (int i = tid * 16; i < WB; i += nthreads * 16) {
        const int row = i / RS;
        const int swz = i ^ ((row & 7) << 4);
        *(uint4*)(lds1 + swz) = *(const uint4*)((const u8*)W1 + i);
        *(uint4*)(lds2 + swz) = *(const uint4*)((const u8*)W2 + i);
    }
    if (OUT_BF16 && tid < 128) lmax[tid] = 0;
    __syncthreads();

    const int arow = r0 + (lane & 15);
    const int crow = (arow < n) ? arow : n - 1;
    const int kof = (lane >> 4) * 8;
    const int kofb = kof * 2;

    bf16x8 a1[KC], a2[KC];
#pragma unroll
    for (int kc = 0; kc < KC; kc++) {
        a1[kc] = *(const bf16x8*)&A[(size_t)crow * lda + kc * 32 + kof];
        a2[kc] = *(const bf16x8*)&B[(size_t)crow * ldb + kc * 32 + kof];
    }
    const int wr = lane & 15;
    const int rbase = r0 + (lane >> 4) * 4;
#pragma unroll
    for (int c = 0; c < 8; c++) {
        f32x4 acc = {0.f, 0.f, 0.f, 0.f};
        const int wrow = c * 16 + wr;
        const int wbase = wrow * RS + kofb;
        const int rsw = (wrow & 7) << 4;
#pragma unroll
        for (int kc = 0; kc < KC; kc++) {
            const int bo = (wbase + kc * 64) ^ rsw;
            acc = __builtin_amdgcn_mfma_f32_16x16x32_bf16(
                a1[kc], *(const bf16x8*)(lds1 + bo), acc, 0, 0, 0);
            acc = __builtin_amdgcn_mfma_f32_16x16x32_bf16(
                a2[kc], *(const bf16x8*)(lds2 + bo), acc, 0, 0, 0);
        }
        const int col = c * 16 + wr;
        const float bv = bias[col];
        float cmax = 0.f;
#pragma unroll
        for (int r = 0; r < 4; r++) {
            const int row = rbase + r;
            if (row < n) {
                float v = acc[r] + bv;
                if (OUT_BF16) {
                    v = fmaxf(v, 0.f);  // relu (L0 layers)
                    cmax = fmaxf(cmax, v);
                    OutB[(size_t)row * 128 + col] = (u16)f2bf(v);
                } else {
                    __builtin_nontemporal_store(v, &OutF[(size_t)row * ldo + col]);
                }
            }
        }
        if (OUT_BF16) atomicMax(&lmax[col], __float_as_int(cmax));
    }
    if (OUT_BF16) {
        __syncthreads();
        if (tid < 128) atomicMax(&colmax[tid], lmax[tid]);
    }
}

// fused L0 gemm: 512 thr (8 waves x 16 rows = 128 rows/block); head = upper
// half of grid. LDS: 2 x 16 KB W + lmax.
__global__ void __launch_bounds__(512) k_gemm_l0_fused(
        const u16* __restrict__ xb,
        const u16* __restrict__ agg0b, const u16* __restrict__ aggUb,
        const u16* __restrict__ Wsb0, const u16* __restrict__ Wnb0,
        const float* __restrict__ b0,
        u16* __restrict__ h1b, u16* __restrict__ u1b,
        int* __restrict__ maxH, int* __restrict__ maxU, int n, int nblk) {
    __shared__ u8 lds1[128 * 64 * 2], lds2[128 * 64 * 2];
    __shared__ int lmax[128];
    const int head = (blockIdx.x >= nblk) ? 1 : 0;
    const int blk = blockIdx.x - head * nblk;
    const int r0 = blk * 128 + (threadIdx.x >> 6) * 16;
    gemm_tile<2, 1>(xb, 64, head ? aggUb : agg0b, 64,
                    Wsb0 + head * 128 * 64, Wnb0 + head * 128 * 64,
                    lds1, lds2, lmax,
                    b0 + head * 128, (float*)nullptr, 0,
                    head ? u1b : h1b, head ? maxU : maxH, n, r0, 512);
}

// fused L1 gemm: 512 thr, 128 rows/block. head0 A=h1b B=aggH(ws, ldb=128);
// head1 A=u1b B=aggU in d_out rows (u16 offset 384, ldb=512). Safe: head0
// writes out bytes [0,512) (disjoint from aggU at [768,1024)); head1 reads
// its B rows into registers before storing bytes [512,1024) (row-disjoint
// across waves). LDS: 2 x 32 KB W.
__global__ void __launch_bounds__(512) k_gemm_l1_fused(
        const u16* __restrict__ h1b, const u16* __restrict__ u1b,
        const u16* __restrict__ aggH, const u16* __restrict__ aggU,
        const u16* __restrict__ Wsb1, const u16* __restrict__ Wnb1,
        const float* __restrict__ b1,
        float* __restrict__ out, int n, int nblk) {
    __shared__ u8 lds1[128 * 128 * 2], lds2[128 * 128 * 2];
    const int head = (blockIdx.x >= nblk) ? 1 : 0;
    const int blk = blockIdx.x - head * nblk;
    const int r0 = blk * 128 + (threadIdx.x >> 6) * 16;
    if (head == 0) {
        gemm_tile<4, 0>(h1b, 128, aggH, 128, Wsb1, Wnb1, lds1, lds2, (int*)nullptr,
                        b1, out, 256, (u16*)nullptr, (int*)nullptr, n, r0, 512);
    } else {
        gemm_tile<4, 0>(u1b, 128, aggU, 512, Wsb1 + 128 * 128, Wnb1 + 128 * 128,
                        lds1, lds2, (int*)nullptr, b1 + 128, out + 128, 256,
                        (u16*)nullptr, (int*)nullptr, n, r0, 512);
    }
}

extern "C" void kernel_launch(void* const* d_in, const int* in_sizes, int n_in,
                              void* d_out, int out_size, void* d_ws, size_t ws_size,
                              hipStream_t stream) {
    const float* x = (const float*)d_in[0];
    const int* src = (const int*)d_in[1];
    const int* dst = (const int*)d_in[2];
    const float* Wn0 = (const float*)d_in[3];
    const float* Ws0 = (const float*)d_in[4];
    const float* b0 = (const float*)d_in[5];
    const float* Wn1 = (const float*)d_in[6];
    const float* Ws1 = (const float*)d_in[7];
    const float* b1 = (const float*)d_in[8];

    const int N = in_sizes[0] / 64;
    const int E = in_sizes[1];
    float* out = (float*)d_out;
    const int NB = (N + 255) >> 8;  // buckets of 256 nodes (must be <= 512)

    // ---- workspace layout (~91 MB) ----
    char* w = (char*)d_ws;
    size_t o = 0;
    auto alloc = [&](size_t bytes) -> void* {
        o = (o + 255) & ~(size_t)255;
        void* p = w + o;
        o += bytes;
        return p;
    };
    int* off_in = (int*)alloc((size_t)(N + 1) * 4);
    int* off_out = (int*)alloc((size_t)(N + 1) * 4);
    int* cntD = (int*)alloc(512 * 4);
    int* cntS = (int*)alloc(512 * 4);
    int* curD = (int*)alloc(512 * 4);
    int* curS = (int*)alloc(512 * 4);
    int* bbaseD = (int*)alloc(513 * 4);
    int* bbaseS = (int*)alloc(513 * 4);
    float* maxH = (float*)alloc(128 * 4);
    float* maxU = (float*)alloc(128 * 4);
    int* adj_in = (int*)alloc((size_t)E * 4);
    int* adj_out = (int*)alloc((size_t)E * 4);
    u16* AGGb = (u16*)alloc((size_t)N * 128 * 2);  // L0 agg 2x[N][64]; L1 aggH
    u16* h1b = (u16*)alloc((size_t)N * 128 * 2);
    u16* u1b = (u16*)alloc((size_t)N * 128 * 2);
    u16* Wsb0 = (u16*)alloc(2 * 128 * 64 * 2);
    u16* Wnb0 = (u16*)alloc(2 * 128 * 64 * 2);
    u16* Wsb1 = (u16*)alloc(2 * 128 * 128 * 2);
    u16* Wnb1 = (u16*)alloc(2 * 128 * 128 * 2);
    (void)ws_size;

    // pair arrays alias h1b/u1b (dead until the L0 gemm runs, after pass D)
    u32* pairsD = (u32*)h1b;
    u32* pairsS = (u32*)u1b;
    // d_out scratch, time-phased:
    //  phase A (prep..L0): xb bf16 @0 (12.8M), xq fp8 @16M (6.4M)
    //  phase B (quant..L1): per-row 1KB slots: h1q[0,128) u1q[128,256)
    //                       aggU[768,1024)
    u16* xb = (u16*)d_out;
    u8* xq = (u8*)d_out + (16 << 20);
    u8* ob = (u8*)d_out;

    const int n4 = N * 64 / 4;
    const int edgeBlocks = ((E + 7) / 8 + 255) / 256;

    // ---- fused prep ----
    k_prep<<<(n4 + 98304 + 255) / 256, 256, 0, stream>>>(
        x, xb, xq, n4, cntD, (int*)maxH, Ws0, Wn0, Ws1, Wn1, Wsb0, Wnb0, Wsb1, Wnb1);

    // ---- CSR build via bucketed counting sort ----
    k_bincnt<<<edgeBlocks, 256, 0, stream>>>(src, dst, cntD, cntS, E, NB);
    k_binscan<<<1, 512, 0, stream>>>(cntD, cntS, bbaseD, bbaseS, curD, curS,
                                     off_in, off_out, NB, N, E);
    k_binscatter<<<edgeBlocks, 256, 0, stream>>>(src, dst, curD, curS, pairsD, pairsS, E, NB);
    k_bucket_csr<<<2 * NB, 256, 0, stream>>>(pairsD, pairsS, bbaseD, bbaseS,
                                             off_in, adj_in, off_out, adj_out, N);

    const int nodeBlocks = (N + 3) / 4;
    const int gemmBlocks128 = (N + 127) / 128;

    // ---- layer 0 ----
    u16* agg0b = AGGb;                    // [N][64]
    u16* aggUb = AGGb + (size_t)N * 64;   // [N][64]
    k_agg_l0_q<<<nodeBlocks, 256, 0, stream>>>(xq, off_in, adj_in, off_out, adj_out,
                                               agg0b, aggUb, N);
    k_gemm_l0_fused<<<2 * gemmBlocks128, 512, 0, stream>>>(
        xb, agg0b, aggUb, Wsb0, Wnb0, b0, h1b, u1b, (int*)maxH, (int*)maxU,
        N, gemmBlocks128);

    // ---- quantize h1/u1 to per-feature uint8 into d_out slots ----
    k_quant<<<(2 * N * 16 + 255) / 256, 256, 0, stream>>>(h1b, u1b, maxH, maxU, ob, N);

    // ---- fused L1 aggregation (aggH -> AGGb ws; aggU -> d_out rows) ----
    k_agg_l1_f<<<nodeBlocks, 256, 0, stream>>>(ob, off_in, adj_in, off_out, adj_out,
                                               maxH, maxU, AGGb, N);

    // ---- fused L1 gemm (both heads, one dispatch, W in LDS) ----
    k_gemm_l1_fused<<<2 * gemmBlocks128, 512, 0, stream>>>(
        h1b, u1b, AGGb, (const u16*)d_out + 384, Wsb1, Wnb1, b1, out, N, gemmBlocks128);
}